// Round 4
// baseline (428.907 us; speedup 1.0000x reference)
//
#include <hip/hip_runtime.h>
#include <cstdint>
#include <cstddef>

typedef __attribute__((ext_vector_type(4))) float f4;
typedef __attribute__((ext_vector_type(8))) short bf16x8;
typedef __attribute__((ext_vector_type(8))) unsigned short u16x8;

// ---------------- helpers ----------------
__device__ __forceinline__ unsigned short f2bf(float x) {
    unsigned u = __float_as_uint(x);
    u += 0x7fffu + ((u >> 16) & 1u);
    return (unsigned short)(u >> 16);
}
__device__ __forceinline__ float bf2f(unsigned short h) {
    return __uint_as_float(((unsigned)h) << 16);
}
__device__ __forceinline__ float fast_exp2(float x) { return __builtin_amdgcn_exp2f(x); }
__device__ __forceinline__ float fast_log2(float x) { return __builtin_amdgcn_logf(x); }
__device__ __forceinline__ void gll16(const void* g, void* l) {
    __builtin_amdgcn_global_load_lds(
        (const __attribute__((address_space(1))) unsigned int*)g,
        (__attribute__((address_space(3))) unsigned int*)l, 16, 0, 0);
}
__device__ __forceinline__ f4 mfma16(bf16x8 a, bf16x8 b, f4 c) {
    return __builtin_amdgcn_mfma_f32_16x16x32_bf16(a, b, c, 0, 0, 0);
}

// ---------------- weight prep: W[K][N] fp32 -> W^T[N][K] bf16 hi/lo ----------------
__global__ __launch_bounds__(256)
void prep_w_kernel(const float* __restrict__ Wq, const float* __restrict__ Wk,
                   const float* __restrict__ Wv, const float* __restrict__ Wo,
                   unsigned short* __restrict__ wt_qkv, unsigned short* __restrict__ wt_o)
{
    const int w = blockIdx.z;
    const float* W = w == 0 ? Wq : (w == 1 ? Wk : (w == 2 ? Wv : Wo));
    unsigned short* hi = (w < 3) ? wt_qkv + (size_t)w * 2097152 : wt_o;
    unsigned short* lo = hi + 1048576;

    const int kb = blockIdx.x << 6, nb = blockIdx.y << 6;
    __shared__ float T[64][68];
    const int tid = threadIdx.x;
    {
        const int r = tid >> 2, c0 = (tid & 3) << 4;
        const float* src = W + (size_t)(kb + r) * 1024 + nb + c0;
        *(f4*)&T[r][c0 + 0]  = *(const f4*)(src + 0);
        *(f4*)&T[r][c0 + 4]  = *(const f4*)(src + 4);
        *(f4*)&T[r][c0 + 8]  = *(const f4*)(src + 8);
        *(f4*)&T[r][c0 + 12] = *(const f4*)(src + 12);
    }
    __syncthreads();
    {
        const int n = tid & 63, ks = (tid >> 6) << 4;
        unsigned short vh[16], vl[16];
        #pragma unroll
        for (int j = 0; j < 16; ++j) {
            const float x = T[ks + j][n];
            const unsigned short h = f2bf(x);
            vh[j] = h;
            vl[j] = f2bf(x - bf2f(h));
        }
        const size_t dst = (size_t)(nb + n) * 1024 + kb + ks;
        *(u16x8*)(hi + dst)     = *(u16x8*)&vh[0];
        *(u16x8*)(hi + dst + 8) = *(u16x8*)&vh[8];
        *(u16x8*)(lo + dst)     = *(u16x8*)&vl[0];
        *(u16x8*)(lo + dst + 8) = *(u16x8*)&vl[8];
    }
}

// ---------------- activation prep: q/k/v fp32 -> bf16 hi/lo ----------------
__global__ __launch_bounds__(256)
void prep_a_kernel(const float* __restrict__ q, const float* __restrict__ k,
                   const float* __restrict__ v,
                   unsigned short* __restrict__ a_hi, unsigned short* __restrict__ a_lo)
{
    const int gid = blockIdx.x * 256 + threadIdx.x;
    const int z = gid >> 18;            // 262144 threads per tensor (4M elems / 16)
    const int rem = gid & 262143;
    const float* src = z == 0 ? q : (z == 1 ? k : v);
    const size_t off = (size_t)rem << 4;
    const float* s = src + off;
    unsigned short* hi = a_hi + ((size_t)z << 22) + off;
    unsigned short* lo = a_lo + ((size_t)z << 22) + off;
    float xs[16];
    *(f4*)&xs[0]  = *(const f4*)(s + 0);
    *(f4*)&xs[4]  = *(const f4*)(s + 4);
    *(f4*)&xs[8]  = *(const f4*)(s + 8);
    *(f4*)&xs[12] = *(const f4*)(s + 12);
    unsigned short hv[16], lv[16];
    #pragma unroll
    for (int j = 0; j < 16; ++j) {
        hv[j] = f2bf(xs[j]);
        lv[j] = f2bf(xs[j] - bf2f(hv[j]));
    }
    *(u16x8*)(hi + 0) = *(u16x8*)&hv[0];
    *(u16x8*)(hi + 8) = *(u16x8*)&hv[8];
    *(u16x8*)(lo + 0) = *(u16x8*)&lv[0];
    *(u16x8*)(lo + 8) = *(u16x8*)&lv[8];
}

// ---------------- 128x128 GEMM core, BK=64, all-gll16 staging ----------------
// A: [4096][1024] bf16 hi/lo. W^T: [1024 n][1024 k] bf16 hi/lo.
// mode 0: head-split hi+lo out; 1: head-split hi only; 2: fp32 out.
__device__ __forceinline__ void gemm_core(
    const unsigned short* __restrict__ AH, const unsigned short* __restrict__ AL,
    const unsigned short* __restrict__ WH, const unsigned short* __restrict__ WL,
    const float* __restrict__ bias, int bm, int bn, int mode,
    unsigned short* __restrict__ o_hi, unsigned short* __restrict__ o_lo,
    float* __restrict__ o_f32, unsigned char* lds)
{
    unsigned char* As = lds;            // 128 rows x 256B  [hi k0..63 | lo k0..63], XOR-swz
    unsigned char* Bs = lds + 32768;
    const int tid = threadIdx.x, lane = tid & 63, wave = tid >> 6;
    const int wm = wave >> 1, wn = wave & 1;
    const int cx = lane & 15, lg = lane >> 4;
    const int m0 = bm << 7, n0 = bn << 7;
    const int l4 = lane >> 4, p4 = lane & 15;

    f4 acc[4][4];
    #pragma unroll
    for (int i = 0; i < 4; ++i)
        #pragma unroll
        for (int j = 0; j < 4; ++j) acc[i][j] = (f4){0.f, 0.f, 0.f, 0.f};

    #pragma unroll 1
    for (int k0 = 0; k0 < 1024; k0 += 64) {
        __syncthreads();
        #pragma unroll
        for (int c = 0; c < 8; ++c) {
            const int cb = (c << 2) + wave;          // 0..31
            const int row = (cb << 2) + l4;          // 0..127
            const int log = p4 ^ ((row & 7) << 1);
            const unsigned short* sa = (log < 8 ? AH : AL)
                + (size_t)(m0 + row) * 1024 + k0 + ((log & 7) << 3);
            gll16(sa, As + (cb << 10) + (lane << 4));
            const unsigned short* sb = (log < 8 ? WH : WL)
                + (size_t)(n0 + row) * 1024 + k0 + ((log & 7) << 3);
            gll16(sb, Bs + (cb << 10) + (lane << 4));
        }
        __syncthreads();
        #pragma unroll
        for (int ks = 0; ks < 2; ++ks) {
            bf16x8 ah[4], al[4], bh[4], bl[4];
            #pragma unroll
            for (int t = 0; t < 4; ++t) {
                const int r = (wm << 6) + (t << 4) + cx;
                const int mk = (r & 7) << 1;
                ah[t] = *(const bf16x8*)(As + r * 256 + (((((ks << 2) + lg))     ^ mk) << 4));
                al[t] = *(const bf16x8*)(As + r * 256 + (((((ks << 2) + lg + 8)) ^ mk) << 4));
                const int n = (wn << 6) + (t << 4) + cx;
                const int mkn = (n & 7) << 1;
                bh[t] = *(const bf16x8*)(Bs + n * 256 + (((((ks << 2) + lg))     ^ mkn) << 4));
                bl[t] = *(const bf16x8*)(Bs + n * 256 + (((((ks << 2) + lg + 8)) ^ mkn) << 4));
            }
            #pragma unroll
            for (int i = 0; i < 4; ++i)
                #pragma unroll
                for (int j = 0; j < 4; ++j) {
                    acc[i][j] = mfma16(ah[i], bh[j], acc[i][j]);
                    acc[i][j] = mfma16(ah[i], bl[j], acc[i][j]);
                    acc[i][j] = mfma16(al[i], bh[j], acc[i][j]);
                }
        }
    }

    float bv[4];
    #pragma unroll
    for (int j = 0; j < 4; ++j) bv[j] = bias[n0 + (wn << 6) + (j << 4) + cx];

    #pragma unroll
    for (int i = 0; i < 4; ++i)
        #pragma unroll
        for (int j = 0; j < 4; ++j) {
            const int n = n0 + (wn << 6) + (j << 4) + cx;
            #pragma unroll
            for (int r = 0; r < 4; ++r) {
                const float val = acc[i][j][r] + bv[j];
                const int m = m0 + (wm << 6) + (i << 4) + (lg << 2) + r;
                if (mode == 2) {
                    o_f32[(size_t)m * 1024 + n] = val;
                } else {
                    const int b = m >> 11, s = m & 2047, hh = n >> 6, d = n & 63;
                    const size_t idx = (((size_t)(b * 16 + hh)) * 2048 + s) * 64 + d;
                    const unsigned short t = f2bf(val);
                    o_hi[idx] = t;
                    if (mode == 0) o_lo[idx] = f2bf(val - bf2f(t));
                }
            }
        }
}

__global__ __launch_bounds__(256)
void qkv_gemm_kernel(const unsigned short* __restrict__ a_hi, const unsigned short* __restrict__ a_lo,
                     const unsigned short* __restrict__ wt_qkv,
                     const float* __restrict__ bq, const float* __restrict__ bk,
                     const float* __restrict__ bv,
                     unsigned short* __restrict__ q_hi, unsigned short* __restrict__ q_lo,
                     unsigned short* __restrict__ k_hi, unsigned short* __restrict__ k_lo,
                     unsigned short* __restrict__ v_hi)
{
    __shared__ __align__(16) unsigned char lds[65536];
    const int f = blockIdx.x;                     // 768, %8==0 -> bijective XCD swizzle
    const int id2 = (f & 7) * 96 + (f >> 3);
    const int z = id2 >> 8;
    const int rem = id2 & 255;
    const int bn = rem >> 5, bm = rem & 31;
    const unsigned short* AH = a_hi + ((size_t)z << 22);
    const unsigned short* AL = a_lo + ((size_t)z << 22);
    const unsigned short* WH = wt_qkv + (size_t)z * 2097152;
    const unsigned short* WL = WH + 1048576;
    const float* bias = z == 0 ? bq : (z == 1 ? bk : bv);
    unsigned short* ohi = z == 0 ? q_hi : (z == 1 ? k_hi : v_hi);
    unsigned short* olo = z == 0 ? q_lo : k_lo;
    gemm_core(AH, AL, WH, WL, bias, bm, bn, (z == 2) ? 1 : 0, ohi, olo, nullptr, lds);
}

__global__ __launch_bounds__(256)
void out_gemm_kernel(const unsigned short* __restrict__ ctx_hi, const unsigned short* __restrict__ ctx_lo,
                     const unsigned short* __restrict__ wt_o,
                     const float* __restrict__ bo, float* __restrict__ out)
{
    __shared__ __align__(16) unsigned char lds[65536];
    const int f = blockIdx.x;                     // 256
    const int id2 = (f & 7) * 32 + (f >> 3);
    const int bn = id2 >> 5, bm = id2 & 31;
    gemm_core(ctx_hi, ctx_lo, wt_o, wt_o + 1048576, bo, bm, bn, 2,
              nullptr, nullptr, out, lds);
}

// ---------------- fused attention: fixed-shift softmax, dbuf K, MFMA ----------------
__global__ __launch_bounds__(256)
void attn_kernel(const unsigned short* __restrict__ q_hi, const unsigned short* __restrict__ q_lo,
                 const unsigned short* __restrict__ k_hi, const unsigned short* __restrict__ k_lo,
                 const unsigned short* __restrict__ v_hi, const float* __restrict__ mask,
                 float* __restrict__ attn,
                 unsigned short* __restrict__ ctx_hi, unsigned short* __restrict__ ctx_lo)
{
    __shared__ __align__(16) unsigned char lds[73728];
    unsigned char* K2 = lds;             // 2 x 16KB: [64 rows][256B hi|lo], swz ((r&7)<<1)
    unsigned char* K1 = lds + 32768;     // 2 x  8KB: [64 rows][128B hi],    swz (r&7)
    unsigned char* Vs = lds + 49152;     // 2 x  8KB: V^T [64 d][128B],      swz (d&7)
    unsigned char* Ps = lds + 65536;     //      8KB: P [64 q][128B],        swz (q&7)

    const int f = blockIdx.x;                       // 1024, %8==0 bijective
    const int swz = (f & 7) * 128 + (f >> 3);
    const int bh = swz >> 5;
    const int q0 = (swz & 31) << 6;
    const int b = bh >> 4, h = bh & 15;
    const int tid = threadIdx.x, lane = tid & 63, wave = tid >> 6;
    const int cx = lane & 15, lg = lane >> 4;
    const int l3 = lane >> 3, p3 = lane & 7;
    const int l4 = lane >> 4, p4 = lane & 15;
    const size_t base = (size_t)bh * 131072;
    const float* mg = mask + (size_t)b * 2048;

    constexpr float C2   = 0.18033688011112042f;     // 0.125 * log2(e)
    constexpr float M2   = -1.4426950408889634e9f;   // -1e9 * log2(e)
    constexpr float MFIX = 4.0f;                     // fixed softmax shift (log2 domain)

    // ---- prologue: stage Q (into K2 area) + K1 tile0 ----
    #pragma unroll
    for (int c = 0; c < 4; ++c) {
        const int cb = (c << 2) + wave;
        const int row = (cb << 2) + l4;
        const int log = p4 ^ ((row & 7) << 1);
        const unsigned short* src = (log < 8 ? q_hi : q_lo)
            + base + (size_t)(q0 + row) * 64 + ((log & 7) << 3);
        gll16(src, K2 + (cb << 10) + (lane << 4));
    }
    #pragma unroll
    for (int c = 0; c < 2; ++c) {
        const int cb = (c << 2) + wave;
        const int row = (cb << 3) + l3;
        const int log = p3 ^ (row & 7);
        const unsigned short* src = k_hi + base + (size_t)row * 64 + (log << 3);
        gll16(src, K1 + (cb << 10) + (lane << 4));
    }
    __syncthreads();

    bf16x8 qa_h[2], qa_l[2];
    {
        const int r = (wave << 4) + cx;
        const int mk = (r & 7) << 1;
        #pragma unroll
        for (int ks = 0; ks < 2; ++ks) {
            qa_h[ks] = *(const bf16x8*)(K2 + r * 256 + (((((ks << 2) + lg))     ^ mk) << 4));
            qa_l[ks] = *(const bf16x8*)(K2 + r * 256 + (((((ks << 2) + lg + 8)) ^ mk) << 4));
        }
    }

    // ---- pass 1: row sums (1-term QK, fixed shift, no shuffles in loop) ----
    float l_loc[4] = {0.f, 0.f, 0.f, 0.f};
    int p = 0;
    #pragma unroll 1
    for (int t = 0; t < 32; ++t) {
        if (t < 31) {
            const int k0n = (t + 1) << 6;
            #pragma unroll
            for (int c = 0; c < 2; ++c) {
                const int cb = (c << 2) + wave;
                const int row = (cb << 3) + l3;
                const int log = p3 ^ (row & 7);
                const unsigned short* src = k_hi + base + (size_t)(k0n + row) * 64 + (log << 3);
                gll16(src, K1 + ((p ^ 1) << 13) + (cb << 10) + (lane << 4));
            }
        }
        const unsigned char* Kc = K1 + (p << 13);
        f4 s[4];
        #pragma unroll
        for (int nt = 0; nt < 4; ++nt) s[nt] = (f4){0.f, 0.f, 0.f, 0.f};
        #pragma unroll
        for (int nt = 0; nt < 4; ++nt) {
            const int kr = (nt << 4) + cx;
            const int mk = kr & 7;
            #pragma unroll
            for (int ks = 0; ks < 2; ++ks) {
                const bf16x8 kb = *(const bf16x8*)(Kc + kr * 128 + (((((ks << 2) + lg)) ^ mk) << 4));
                s[nt] = mfma16(qa_h[ks], kb, s[nt]);
            }
        }
        const int k0 = t << 6;
        float ml[4];
        #pragma unroll
        for (int nt = 0; nt < 4; ++nt) ml[nt] = fmaf(mg[k0 + (nt << 4) + cx], M2, -MFIX);
        #pragma unroll
        for (int r = 0; r < 4; ++r) {
            l_loc[r] += fast_exp2(fmaf(s[0][r], C2, ml[0]))
                      + fast_exp2(fmaf(s[1][r], C2, ml[1]))
                      + fast_exp2(fmaf(s[2][r], C2, ml[2]))
                      + fast_exp2(fmaf(s[3][r], C2, ml[3]));
        }
        __syncthreads();
        p ^= 1;
    }

    float ofs[4];
    #pragma unroll
    for (int r = 0; r < 4; ++r) {
        float ss = l_loc[r];
        ss += __shfl_xor(ss, 1);
        ss += __shfl_xor(ss, 2);
        ss += __shfl_xor(ss, 4);
        ss += __shfl_xor(ss, 8);
        ofs[r] = MFIX + fast_log2(ss);   // P = exp2(lgt - ofs)
    }

    // ---- pass 2: attn write + PV ----
    #pragma unroll
    for (int c = 0; c < 4; ++c) {
        const int cb = (c << 2) + wave;
        const int row = (cb << 2) + l4;
        const int log = p4 ^ ((row & 7) << 1);
        const unsigned short* src = (log < 8 ? k_hi : k_lo)
            + base + (size_t)row * 64 + ((log & 7) << 3);
        gll16(src, K2 + (cb << 10) + (lane << 4));
    }
    u16x8 vr0 = *(const u16x8*)(v_hi + base + (size_t)lane * 64 + (wave << 4));
    u16x8 vr1 = *(const u16x8*)(v_hi + base + (size_t)lane * 64 + (wave << 4) + 8);
    __syncthreads();

    f4 cacc[4];
    #pragma unroll
    for (int nt = 0; nt < 4; ++nt) cacc[nt] = (f4){0.f, 0.f, 0.f, 0.f};

    p = 0;
    #pragma unroll 1
    for (int t = 0; t < 32; ++t) {
        const int k0 = t << 6;
        // [A] stage next K tile (hi+lo)
        if (t < 31) {
            #pragma unroll
            for (int c = 0; c < 4; ++c) {
                const int cb = (c << 2) + wave;
                const int row = (cb << 2) + l4;
                const int log = p4 ^ ((row & 7) << 1);
                const unsigned short* src = (log < 8 ? k_hi : k_lo)
                    + base + (size_t)(k0 + 64 + row) * 64 + ((log & 7) << 3);
                gll16(src, K2 + ((p ^ 1) << 14) + (cb << 10) + (lane << 4));
            }
        }
        // [A2] next V -> regs (latency hidden under QK)
        u16x8 vn0 = vr0, vn1 = vr1;
        if (t < 31) {
            vn0 = *(const u16x8*)(v_hi + base + (size_t)(k0 + 64 + lane) * 64 + (wave << 4));
            vn1 = *(const u16x8*)(v_hi + base + (size_t)(k0 + 64 + lane) * 64 + (wave << 4) + 8);
        }
        // [B] QK^T 3-term on K2[p]
        const unsigned char* Kc = K2 + (p << 14);
        f4 s[4];
        #pragma unroll
        for (int nt = 0; nt < 4; ++nt) s[nt] = (f4){0.f, 0.f, 0.f, 0.f};
        #pragma unroll
        for (int nt = 0; nt < 4; ++nt) {
            const int kr = (nt << 4) + cx;
            const int mk = (kr & 7) << 1;
            #pragma unroll
            for (int ks = 0; ks < 2; ++ks) {
                const bf16x8 kh8 = *(const bf16x8*)(Kc + kr * 256 + (((((ks << 2) + lg))     ^ mk) << 4));
                const bf16x8 kl8 = *(const bf16x8*)(Kc + kr * 256 + (((((ks << 2) + lg + 8)) ^ mk) << 4));
                s[nt] = mfma16(qa_h[ks], kh8, s[nt]);
                s[nt] = mfma16(qa_h[ks], kl8, s[nt]);
                s[nt] = mfma16(qa_l[ks], kh8, s[nt]);
            }
        }
        // [C] V^T stage into Vs[p] from regs
        {
            const int slot = lane >> 3, sb = (lane & 7) << 1;
            unsigned char* Vb = Vs + (p << 13);
            #pragma unroll
            for (int j = 0; j < 8; ++j) {
                const int d = (wave << 4) + j;
                *(unsigned short*)(Vb + d * 128 + ((slot ^ (d & 7)) << 4) + sb) = (unsigned short)vr0[j];
                const int d2 = (wave << 4) + 8 + j;
                *(unsigned short*)(Vb + d2 * 128 + ((slot ^ (d2 & 7)) << 4) + sb) = (unsigned short)vr1[j];
            }
        }
        // [E] probabilities: attn store + Ps write
        float mk2[4];
        #pragma unroll
        for (int nt = 0; nt < 4; ++nt) mk2[nt] = mg[k0 + (nt << 4) + cx] * M2;
        #pragma unroll
        for (int nt = 0; nt < 4; ++nt) {
            #pragma unroll
            for (int r = 0; r < 4; ++r) {
                const float pr = fast_exp2(fmaf(s[nt][r], C2, mk2[nt]) - ofs[r]);
                const int qrow = (wave << 4) + (lg << 2) + r;
                attn[((size_t)bh * 2048 + q0 + qrow) * 2048 + k0 + (nt << 4) + cx] = pr;
                const int col = (nt << 4) + cx;
                *(unsigned short*)(Ps + qrow * 128 + (((col >> 3) ^ (qrow & 7)) << 4)
                                   + ((col & 7) << 1)) = f2bf(pr);
            }
        }
        __syncthreads();
        // [G] PV
        {
            const int qr = (wave << 4) + cx;
            #pragma unroll
            for (int ks = 0; ks < 2; ++ks) {
                const bf16x8 pa = *(const bf16x8*)(Ps + qr * 128 + (((((ks << 2) + lg)) ^ (qr & 7)) << 4));
                #pragma unroll
                for (int nt = 0; nt < 4; ++nt) {
                    const int dr = (nt << 4) + cx;
                    const bf16x8 vb = *(const bf16x8*)(Vs + (p << 13) + dr * 128
                                                       + (((((ks << 2) + lg)) ^ (dr & 7)) << 4));
                    cacc[nt] = mfma16(pa, vb, cacc[nt]);
                }
            }
        }
        __syncthreads();
        vr0 = vn0; vr1 = vn1;
        p ^= 1;
    }

    // ---- ctx out (bf16 hi/lo, feeds out_gemm directly) ----
    #pragma unroll
    for (int nt = 0; nt < 4; ++nt)
        #pragma unroll
        for (int r = 0; r < 4; ++r) {
            const int srow = q0 + (wave << 4) + (lg << 2) + r;
            const int d = (h << 6) + (nt << 4) + cx;
            const size_t cidx = ((size_t)b * 2048 + srow) * 1024 + d;
            const float val = cacc[nt][r];
            const unsigned short hv = f2bf(val);
            ctx_hi[cidx] = hv;
            ctx_lo[cidx] = f2bf(val - bf2f(hv));
        }
}

// ---------------- launcher ----------------
extern "C" void kernel_launch(void* const* d_in, const int* in_sizes, int n_in,
                              void* d_out, int out_size, void* d_ws, size_t ws_size,
                              hipStream_t stream)
{
    const float* v_in = (const float*)d_in[0];
    const float* k_in = (const float*)d_in[1];
    const float* q_in = (const float*)d_in[2];
    const float* mask = (const float*)d_in[3];
    const float* Wq = (const float*)d_in[4];
    const float* bq = (const float*)d_in[5];
    const float* Wk = (const float*)d_in[6];
    const float* bk = (const float*)d_in[7];
    const float* Wv = (const float*)d_in[8];
    const float* bv = (const float*)d_in[9];
    const float* Wo = (const float*)d_in[10];
    const float* bo = (const float*)d_in[11];

    float* out  = (float*)d_out;                    // [2,2048,1024]
    float* attn = out + (size_t)4194304;            // [2,16,2048,2048] = 512 MB

    unsigned char* ws = (unsigned char*)d_ws;       // 60 MB used
    unsigned short* wt_o   = (unsigned short*)(ws);
    unsigned short* q_hi   = (unsigned short*)(ws + (size_t)(4)  * 1048576);
    unsigned short* q_lo   = (unsigned short*)(ws + (size_t)(12) * 1048576);
    unsigned short* k_hi   = (unsigned short*)(ws + (size_t)(20) * 1048576);
    unsigned short* k_lo   = (unsigned short*)(ws + (size_t)(28) * 1048576);
    unsigned short* v_hi   = (unsigned short*)(ws + (size_t)(36) * 1048576);
    unsigned short* ctx_hi = (unsigned short*)(ws + (size_t)(44) * 1048576);
    unsigned short* ctx_lo = (unsigned short*)(ws + (size_t)(52) * 1048576);

    // dead scratch inside the attn output region (overwritten by attn_kernel later)
    unsigned short* a_hi   = (unsigned short*)(attn + (size_t)60  * 1048576);
    unsigned short* a_lo   = (unsigned short*)(attn + (size_t)70  * 1048576);
    unsigned short* wt_qkv = (unsigned short*)(attn + (size_t)100 * 1048576);

    prep_w_kernel<<<dim3(16, 16, 4), 256, 0, stream>>>(Wq, Wk, Wv, Wo, wt_qkv, wt_o);
    prep_a_kernel<<<3072, 256, 0, stream>>>(q_in, k_in, v_in, a_hi, a_lo);
    qkv_gemm_kernel<<<768, 256, 0, stream>>>(a_hi, a_lo, wt_qkv, bq, bk, bv,
                                             q_hi, q_lo, k_hi, k_lo, v_hi);
    attn_kernel<<<1024, 256, 0, stream>>>(q_hi, q_lo, k_hi, k_lo, v_hi, mask,
                                          attn, ctx_hi, ctx_lo);
    out_gemm_kernel<<<256, 256, 0, stream>>>(ctx_hi, ctx_lo, wt_o, bo, out);
}

// Round 5
// 355.932 us; speedup vs baseline: 1.2050x; 1.2050x over previous
//
#include <hip/hip_runtime.h>
#include <cstdint>
#include <cstddef>

typedef __attribute__((ext_vector_type(4))) float f4;
typedef __attribute__((ext_vector_type(8))) short bf16x8;
typedef __attribute__((ext_vector_type(8))) unsigned short u16x8;

// ---------------- helpers ----------------
__device__ __forceinline__ unsigned short f2bf(float x) {
    unsigned u = __float_as_uint(x);
    u += 0x7fffu + ((u >> 16) & 1u);
    return (unsigned short)(u >> 16);
}
__device__ __forceinline__ float bf2f(unsigned short h) {
    return __uint_as_float(((unsigned)h) << 16);
}
__device__ __forceinline__ float fast_exp2(float x) { return __builtin_amdgcn_exp2f(x); }
__device__ __forceinline__ float fast_log2(float x) { return __builtin_amdgcn_logf(x); }
__device__ __forceinline__ void gll16(const void* g, void* l) {
    __builtin_amdgcn_global_load_lds(
        (const __attribute__((address_space(1))) unsigned int*)g,
        (__attribute__((address_space(3))) unsigned int*)l, 16, 0, 0);
}
__device__ __forceinline__ f4 mfma16(bf16x8 a, bf16x8 b, f4 c) {
    return __builtin_amdgcn_mfma_f32_16x16x32_bf16(a, b, c, 0, 0, 0);
}

// ---------------- weight prep: W[K][N] fp32 -> W^T[N][K] bf16 hi/lo ----------------
__global__ __launch_bounds__(256)
void prep_w_kernel(const float* __restrict__ Wq, const float* __restrict__ Wk,
                   const float* __restrict__ Wv, const float* __restrict__ Wo,
                   unsigned short* __restrict__ wt_qkv, unsigned short* __restrict__ wt_o)
{
    const int w = blockIdx.z;
    const float* W = w == 0 ? Wq : (w == 1 ? Wk : (w == 2 ? Wv : Wo));
    unsigned short* hi = (w < 3) ? wt_qkv + (size_t)w * 2097152 : wt_o;
    unsigned short* lo = hi + 1048576;

    const int kb = blockIdx.x << 6, nb = blockIdx.y << 6;
    __shared__ float T[64][68];
    const int tid = threadIdx.x;
    {
        const int r = tid >> 2, c0 = (tid & 3) << 4;
        const float* src = W + (size_t)(kb + r) * 1024 + nb + c0;
        *(f4*)&T[r][c0 + 0]  = *(const f4*)(src + 0);
        *(f4*)&T[r][c0 + 4]  = *(const f4*)(src + 4);
        *(f4*)&T[r][c0 + 8]  = *(const f4*)(src + 8);
        *(f4*)&T[r][c0 + 12] = *(const f4*)(src + 12);
    }
    __syncthreads();
    {
        const int n = tid & 63, ks = (tid >> 6) << 4;
        unsigned short vh[16], vl[16];
        #pragma unroll
        for (int j = 0; j < 16; ++j) {
            const float x = T[ks + j][n];
            const unsigned short h = f2bf(x);
            vh[j] = h;
            vl[j] = f2bf(x - bf2f(h));
        }
        const size_t dst = (size_t)(nb + n) * 1024 + kb + ks;
        *(u16x8*)(hi + dst)     = *(u16x8*)&vh[0];
        *(u16x8*)(hi + dst + 8) = *(u16x8*)&vh[8];
        *(u16x8*)(lo + dst)     = *(u16x8*)&vl[0];
        *(u16x8*)(lo + dst + 8) = *(u16x8*)&vl[8];
    }
}

// ---------------- activation prep: q/k/v fp32 -> bf16 hi/lo ----------------
__global__ __launch_bounds__(256)
void prep_a_kernel(const float* __restrict__ q, const float* __restrict__ k,
                   const float* __restrict__ v,
                   unsigned short* __restrict__ a_hi, unsigned short* __restrict__ a_lo)
{
    const int gid = blockIdx.x * 256 + threadIdx.x;
    const int z = gid >> 18;
    const int rem = gid & 262143;
    const float* src = z == 0 ? q : (z == 1 ? k : v);
    const size_t off = (size_t)rem << 4;
    const float* s = src + off;
    unsigned short* hi = a_hi + ((size_t)z << 22) + off;
    unsigned short* lo = a_lo + ((size_t)z << 22) + off;
    float xs[16];
    *(f4*)&xs[0]  = *(const f4*)(s + 0);
    *(f4*)&xs[4]  = *(const f4*)(s + 4);
    *(f4*)&xs[8]  = *(const f4*)(s + 8);
    *(f4*)&xs[12] = *(const f4*)(s + 12);
    unsigned short hv[16], lv[16];
    #pragma unroll
    for (int j = 0; j < 16; ++j) {
        hv[j] = f2bf(xs[j]);
        lv[j] = f2bf(xs[j] - bf2f(hv[j]));
    }
    *(u16x8*)(hi + 0) = *(u16x8*)&hv[0];
    *(u16x8*)(hi + 8) = *(u16x8*)&hv[8];
    *(u16x8*)(lo + 0) = *(u16x8*)&lv[0];
    *(u16x8*)(lo + 8) = *(u16x8*)&lv[8];
}

// ---------------- 128x128 GEMM core, BK=64, all-gll16 staging ----------------
// mode 1: head-split bf16 hi out; mode 2: fp32 out.
__device__ __forceinline__ void gemm_core(
    const unsigned short* __restrict__ AH, const unsigned short* __restrict__ AL,
    const unsigned short* __restrict__ WH, const unsigned short* __restrict__ WL,
    const float* __restrict__ bias, int bm, int bn, int mode,
    unsigned short* __restrict__ o_hi, float* __restrict__ o_f32, unsigned char* lds)
{
    unsigned char* As = lds;            // 128 rows x 256B  [hi k0..63 | lo k0..63], XOR-swz
    unsigned char* Bs = lds + 32768;
    const int tid = threadIdx.x, lane = tid & 63, wave = tid >> 6;
    const int wm = wave >> 1, wn = wave & 1;
    const int cx = lane & 15, lg = lane >> 4;
    const int m0 = bm << 7, n0 = bn << 7;
    const int l4 = lane >> 4, p4 = lane & 15;

    f4 acc[4][4];
    #pragma unroll
    for (int i = 0; i < 4; ++i)
        #pragma unroll
        for (int j = 0; j < 4; ++j) acc[i][j] = (f4){0.f, 0.f, 0.f, 0.f};

    #pragma unroll 1
    for (int k0 = 0; k0 < 1024; k0 += 64) {
        __syncthreads();
        #pragma unroll
        for (int c = 0; c < 8; ++c) {
            const int cb = (c << 2) + wave;
            const int row = (cb << 2) + l4;
            const int lgx = p4 ^ ((row & 7) << 1);
            const unsigned short* sa = (lgx < 8 ? AH : AL)
                + (size_t)(m0 + row) * 1024 + k0 + ((lgx & 7) << 3);
            gll16(sa, As + (cb << 10) + (lane << 4));
            const unsigned short* sb = (lgx < 8 ? WH : WL)
                + (size_t)(n0 + row) * 1024 + k0 + ((lgx & 7) << 3);
            gll16(sb, Bs + (cb << 10) + (lane << 4));
        }
        __syncthreads();
        #pragma unroll
        for (int ks = 0; ks < 2; ++ks) {
            bf16x8 ah[4], al[4], bh[4], bl[4];
            #pragma unroll
            for (int t = 0; t < 4; ++t) {
                const int r = (wm << 6) + (t << 4) + cx;
                const int mk = (r & 7) << 1;
                ah[t] = *(const bf16x8*)(As + r * 256 + (((((ks << 2) + lg))     ^ mk) << 4));
                al[t] = *(const bf16x8*)(As + r * 256 + (((((ks << 2) + lg + 8)) ^ mk) << 4));
                const int n = (wn << 6) + (t << 4) + cx;
                const int mkn = (n & 7) << 1;
                bh[t] = *(const bf16x8*)(Bs + n * 256 + (((((ks << 2) + lg))     ^ mkn) << 4));
                bl[t] = *(const bf16x8*)(Bs + n * 256 + (((((ks << 2) + lg + 8)) ^ mkn) << 4));
            }
            #pragma unroll
            for (int i = 0; i < 4; ++i)
                #pragma unroll
                for (int j = 0; j < 4; ++j) {
                    acc[i][j] = mfma16(ah[i], bh[j], acc[i][j]);
                    acc[i][j] = mfma16(ah[i], bl[j], acc[i][j]);
                    acc[i][j] = mfma16(al[i], bh[j], acc[i][j]);
                }
        }
    }

    float bv[4];
    #pragma unroll
    for (int j = 0; j < 4; ++j) bv[j] = bias[n0 + (wn << 6) + (j << 4) + cx];

    #pragma unroll
    for (int i = 0; i < 4; ++i)
        #pragma unroll
        for (int j = 0; j < 4; ++j) {
            const int n = n0 + (wn << 6) + (j << 4) + cx;
            #pragma unroll
            for (int r = 0; r < 4; ++r) {
                const float val = acc[i][j][r] + bv[j];
                const int m = m0 + (wm << 6) + (i << 4) + (lg << 2) + r;
                if (mode == 2) {
                    o_f32[(size_t)m * 1024 + n] = val;
                } else {
                    const int b = m >> 11, s = m & 2047, hh = n >> 6, d = n & 63;
                    const size_t idx = (((size_t)(b * 16 + hh)) * 2048 + s) * 64 + d;
                    o_hi[idx] = f2bf(val);
                }
            }
        }
}

__global__ __launch_bounds__(256)
void qkv_gemm_kernel(const unsigned short* __restrict__ a_hi, const unsigned short* __restrict__ a_lo,
                     const unsigned short* __restrict__ wt_qkv,
                     const float* __restrict__ bq, const float* __restrict__ bk,
                     const float* __restrict__ bv,
                     unsigned short* __restrict__ q_hi, unsigned short* __restrict__ k_hi,
                     unsigned short* __restrict__ v_hi)
{
    __shared__ __align__(16) unsigned char lds[65536];
    const int f = blockIdx.x;                     // 768, %8==0 -> bijective XCD swizzle
    const int id2 = (f & 7) * 96 + (f >> 3);
    const int z = id2 >> 8;
    const int rem = id2 & 255;
    const int bn = rem >> 5, bm = rem & 31;
    const unsigned short* AH = a_hi + ((size_t)z << 22);
    const unsigned short* AL = a_lo + ((size_t)z << 22);
    const unsigned short* WH = wt_qkv + (size_t)z * 2097152;
    const unsigned short* WL = WH + 1048576;
    const float* bias = z == 0 ? bq : (z == 1 ? bk : bv);
    unsigned short* ohi = z == 0 ? q_hi : (z == 1 ? k_hi : v_hi);
    gemm_core(AH, AL, WH, WL, bias, bm, bn, 1, ohi, nullptr, lds);
}

__global__ __launch_bounds__(256)
void out_gemm_kernel(const unsigned short* __restrict__ ctx_hi, const unsigned short* __restrict__ ctx_lo,
                     const unsigned short* __restrict__ wt_o,
                     const float* __restrict__ bo, float* __restrict__ out)
{
    __shared__ __align__(16) unsigned char lds[65536];
    const int f = blockIdx.x;                     // 256
    const int id2 = (f & 7) * 32 + (f >> 3);
    const int bn = id2 >> 5, bm = id2 & 31;
    gemm_core(ctx_hi, ctx_lo, wt_o, wt_o + 1048576, bo, bm, bn, 2, nullptr, out, lds);
}

// ---------------- fused attention: 1-term QK, fixed-shift softmax, 32 KB LDS ----------------
__global__ __launch_bounds__(256, 4)
void attn_kernel(const unsigned short* __restrict__ q_hi, const unsigned short* __restrict__ k_hi,
                 const unsigned short* __restrict__ v_hi, const float* __restrict__ mask,
                 float* __restrict__ attn,
                 unsigned short* __restrict__ ctx_hi, unsigned short* __restrict__ ctx_lo)
{
    __shared__ __align__(16) unsigned char lds[32768];
    unsigned char* K1 = lds;             // 2 x 8KB: K [64 rows][128B], swz (r&7)
    unsigned char* Vs = lds + 16384;     //     8KB: V^T [64 d][128B s], swz (d&7)
    unsigned char* Ps = lds + 24576;     //     8KB: P [64 q][128B k] (Q staged here at prologue)

    const int f = blockIdx.x;                       // 1024, %8==0 bijective
    const int swz = (f & 7) * 128 + (f >> 3);
    const int bh = swz >> 5;
    const int q0 = (swz & 31) << 6;
    const int b = bh >> 4, h = bh & 15;
    const int tid = threadIdx.x, lane = tid & 63, wave = tid >> 6;
    const int cx = lane & 15, lg = lane >> 4;
    const int l3 = lane >> 3, p3 = lane & 7;
    const size_t base = (size_t)bh * 131072;
    const float* mg = mask + (size_t)b * 2048;

    constexpr float C2   = 0.18033688011112042f;     // 0.125 * log2(e)
    constexpr float M2   = -1.4426950408889634e9f;   // -1e9 * log2(e)
    constexpr float MFIX = 4.0f;                     // fixed softmax shift (log2 domain)

    // ---- prologue: Q -> Ps, K tile0 -> K1[0] ----
    #pragma unroll
    for (int c = 0; c < 2; ++c) {
        const int cb = (c << 2) + wave;
        const int row = (cb << 3) + l3;
        const int lgx = p3 ^ (row & 7);
        gll16(q_hi + base + (size_t)(q0 + row) * 64 + (lgx << 3),
              Ps + (cb << 10) + (lane << 4));
        gll16(k_hi + base + (size_t)row * 64 + (lgx << 3),
              K1 + (cb << 10) + (lane << 4));
    }
    __syncthreads();

    bf16x8 qa_h[2];
    {
        const int r = (wave << 4) + cx;
        const int mk = r & 7;
        #pragma unroll
        for (int ks = 0; ks < 2; ++ks)
            qa_h[ks] = *(const bf16x8*)(Ps + r * 128 + (((((ks << 2) + lg)) ^ mk) << 4));
    }

    // ---- pass 1: row sums (fixed shift, no shuffles in loop) ----
    float l_loc[4] = {0.f, 0.f, 0.f, 0.f};
    #pragma unroll 1
    for (int t = 0; t < 32; ++t) {
        const int p = t & 1;
        if (t < 31) {
            const int k0n = (t + 1) << 6;
            #pragma unroll
            for (int c = 0; c < 2; ++c) {
                const int cb = (c << 2) + wave;
                const int row = (cb << 3) + l3;
                const int lgx = p3 ^ (row & 7);
                gll16(k_hi + base + (size_t)(k0n + row) * 64 + (lgx << 3),
                      K1 + ((p ^ 1) << 13) + (cb << 10) + (lane << 4));
            }
        }
        const unsigned char* Kc = K1 + (p << 13);
        f4 s[4];
        #pragma unroll
        for (int nt = 0; nt < 4; ++nt) s[nt] = (f4){0.f, 0.f, 0.f, 0.f};
        #pragma unroll
        for (int nt = 0; nt < 4; ++nt) {
            const int kr = (nt << 4) + cx;
            const int mk = kr & 7;
            #pragma unroll
            for (int ks = 0; ks < 2; ++ks) {
                const bf16x8 kb = *(const bf16x8*)(Kc + kr * 128 + (((((ks << 2) + lg)) ^ mk) << 4));
                s[nt] = mfma16(qa_h[ks], kb, s[nt]);
            }
        }
        const int k0 = t << 6;
        float ml[4];
        #pragma unroll
        for (int nt = 0; nt < 4; ++nt) ml[nt] = fmaf(mg[k0 + (nt << 4) + cx], M2, -MFIX);
        #pragma unroll
        for (int r = 0; r < 4; ++r) {
            l_loc[r] += fast_exp2(fmaf(s[0][r], C2, ml[0]))
                      + fast_exp2(fmaf(s[1][r], C2, ml[1]))
                      + fast_exp2(fmaf(s[2][r], C2, ml[2]))
                      + fast_exp2(fmaf(s[3][r], C2, ml[3]));
        }
        __syncthreads();
    }

    float ofs[4];
    #pragma unroll
    for (int r = 0; r < 4; ++r) {
        float ss = l_loc[r];
        ss += __shfl_xor(ss, 1);
        ss += __shfl_xor(ss, 2);
        ss += __shfl_xor(ss, 4);
        ss += __shfl_xor(ss, 8);
        ofs[r] = MFIX + fast_log2(ss);   // P = exp2(lgt - ofs)
    }

    // ---- pass 2 prologue: K tile0 -> K1[0], V tile0 -> regs ----
    #pragma unroll
    for (int c = 0; c < 2; ++c) {
        const int cb = (c << 2) + wave;
        const int row = (cb << 3) + l3;
        const int lgx = p3 ^ (row & 7);
        gll16(k_hi + base + (size_t)row * 64 + (lgx << 3),
              K1 + (cb << 10) + (lane << 4));
    }
    u16x8 vr0 = *(const u16x8*)(v_hi + base + (size_t)lane * 64 + (wave << 4));
    u16x8 vr1 = *(const u16x8*)(v_hi + base + (size_t)lane * 64 + (wave << 4) + 8);
    __syncthreads();

    f4 cacc[4];
    #pragma unroll
    for (int nt = 0; nt < 4; ++nt) cacc[nt] = (f4){0.f, 0.f, 0.f, 0.f};

    #pragma unroll 1
    for (int t = 0; t < 32; ++t) {
        const int k0 = t << 6;
        const int p = t & 1;
        // [A] prefetch next K tile
        if (t < 31) {
            #pragma unroll
            for (int c = 0; c < 2; ++c) {
                const int cb = (c << 2) + wave;
                const int row = (cb << 3) + l3;
                const int lgx = p3 ^ (row & 7);
                gll16(k_hi + base + (size_t)(k0 + 64 + row) * 64 + (lgx << 3),
                      K1 + ((p ^ 1) << 13) + (cb << 10) + (lane << 4));
            }
        }
        // [A2] next V -> regs
        u16x8 vn0 = vr0, vn1 = vr1;
        if (t < 31) {
            vn0 = *(const u16x8*)(v_hi + base + (size_t)(k0 + 64 + lane) * 64 + (wave << 4));
            vn1 = *(const u16x8*)(v_hi + base + (size_t)(k0 + 64 + lane) * 64 + (wave << 4) + 8);
        }
        // [B] QK^T 1-term on K1[p]
        const unsigned char* Kc = K1 + (p << 13);
        f4 s[4];
        #pragma unroll
        for (int nt = 0; nt < 4; ++nt) s[nt] = (f4){0.f, 0.f, 0.f, 0.f};
        #pragma unroll
        for (int nt = 0; nt < 4; ++nt) {
            const int kr = (nt << 4) + cx;
            const int mk = kr & 7;
            #pragma unroll
            for (int ks = 0; ks < 2; ++ks) {
                const bf16x8 kb = *(const bf16x8*)(Kc + kr * 128 + (((((ks << 2) + lg)) ^ mk) << 4));
                s[nt] = mfma16(qa_h[ks], kb, s[nt]);
            }
        }
        // [C] V^T stage into Vs (single buffer; prev reads fenced by last barrier)
        {
            const int slot = lane >> 3, sb = (lane & 7) << 1;
            #pragma unroll
            for (int j = 0; j < 8; ++j) {
                const int d = (wave << 4) + j;
                *(unsigned short*)(Vs + d * 128 + ((slot ^ (d & 7)) << 4) + sb) = (unsigned short)vr0[j];
                const int d2 = d + 8;
                *(unsigned short*)(Vs + d2 * 128 + ((slot ^ (d2 & 7)) << 4) + sb) = (unsigned short)vr1[j];
            }
        }
        // [E] probabilities: attn store + Ps write
        float mk2[4];
        #pragma unroll
        for (int nt = 0; nt < 4; ++nt) mk2[nt] = mg[k0 + (nt << 4) + cx] * M2;
        #pragma unroll
        for (int nt = 0; nt < 4; ++nt) {
            #pragma unroll
            for (int r = 0; r < 4; ++r) {
                const float pr = fast_exp2(fmaf(s[nt][r], C2, mk2[nt]) - ofs[r]);
                const int qrow = (wave << 4) + (lg << 2) + r;
                attn[((size_t)bh * 2048 + q0 + qrow) * 2048 + k0 + (nt << 4) + cx] = pr;
                const int col = (nt << 4) + cx;
                *(unsigned short*)(Ps + qrow * 128 + (((col >> 3) ^ (qrow & 7)) << 4)
                                   + ((col & 7) << 1)) = f2bf(pr);
            }
        }
        __syncthreads();
        // [G] PV
        {
            const int qr = (wave << 4) + cx;
            #pragma unroll
            for (int ks = 0; ks < 2; ++ks) {
                const bf16x8 pa = *(const bf16x8*)(Ps + qr * 128 + (((((ks << 2) + lg)) ^ (qr & 7)) << 4));
                #pragma unroll
                for (int nt = 0; nt < 4; ++nt) {
                    const int dr = (nt << 4) + cx;
                    const bf16x8 vb = *(const bf16x8*)(Vs + dr * 128 + (((((ks << 2) + lg)) ^ (dr & 7)) << 4));
                    cacc[nt] = mfma16(pa, vb, cacc[nt]);
                }
            }
        }
        __syncthreads();
        vr0 = vn0; vr1 = vn1;
    }

    // ---- ctx out (bf16 hi/lo, feeds out_gemm directly) ----
    #pragma unroll
    for (int nt = 0; nt < 4; ++nt)
        #pragma unroll
        for (int r = 0; r < 4; ++r) {
            const int srow = q0 + (wave << 4) + (lg << 2) + r;
            const int d = (h << 6) + (nt << 4) + cx;
            const size_t cidx = ((size_t)b * 2048 + srow) * 1024 + d;
            const float val = cacc[nt][r];
            const unsigned short hv = f2bf(val);
            ctx_hi[cidx] = hv;
            ctx_lo[cidx] = f2bf(val - bf2f(hv));
        }
}

// ---------------- launcher ----------------
extern "C" void kernel_launch(void* const* d_in, const int* in_sizes, int n_in,
                              void* d_out, int out_size, void* d_ws, size_t ws_size,
                              hipStream_t stream)
{
    const float* v_in = (const float*)d_in[0];
    const float* k_in = (const float*)d_in[1];
    const float* q_in = (const float*)d_in[2];
    const float* mask = (const float*)d_in[3];
    const float* Wq = (const float*)d_in[4];
    const float* bq = (const float*)d_in[5];
    const float* Wk = (const float*)d_in[6];
    const float* bk = (const float*)d_in[7];
    const float* Wv = (const float*)d_in[8];
    const float* bv = (const float*)d_in[9];
    const float* Wo = (const float*)d_in[10];
    const float* bo = (const float*)d_in[11];

    float* out  = (float*)d_out;                    // [2,2048,1024]
    float* attn = out + (size_t)4194304;            // [2,16,2048,2048] = 512 MB

    unsigned char* ws = (unsigned char*)d_ws;       // 44 MB used
    unsigned short* wt_o   = (unsigned short*)(ws);
    unsigned short* q_hi   = (unsigned short*)(ws + (size_t)(4)  * 1048576);
    unsigned short* k_hi   = (unsigned short*)(ws + (size_t)(12) * 1048576);
    unsigned short* v_hi   = (unsigned short*)(ws + (size_t)(20) * 1048576);
    unsigned short* ctx_hi = (unsigned short*)(ws + (size_t)(28) * 1048576);
    unsigned short* ctx_lo = (unsigned short*)(ws + (size_t)(36) * 1048576);

    // dead scratch inside the attn output region (overwritten by attn_kernel later)
    unsigned short* a_hi   = (unsigned short*)(attn + (size_t)60  * 1048576);
    unsigned short* a_lo   = (unsigned short*)(attn + (size_t)70  * 1048576);
    unsigned short* wt_qkv = (unsigned short*)(attn + (size_t)100 * 1048576);

    prep_w_kernel<<<dim3(16, 16, 4), 256, 0, stream>>>(Wq, Wk, Wv, Wo, wt_qkv, wt_o);
    prep_a_kernel<<<3072, 256, 0, stream>>>(q_in, k_in, v_in, a_hi, a_lo);
    qkv_gemm_kernel<<<768, 256, 0, stream>>>(a_hi, a_lo, wt_qkv, bq, bk, bv,
                                             q_hi, k_hi, v_hi);
    attn_kernel<<<1024, 256, 0, stream>>>(q_hi, k_hi, v_hi, mask,
                                          attn, ctx_hi, ctx_lo);
    out_gemm_kernel<<<256, 256, 0, stream>>>(ctx_hi, ctx_lo, wt_o, bo, out);
}

// Round 6
// 300.494 us; speedup vs baseline: 1.4273x; 1.1845x over previous
//
#include <hip/hip_runtime.h>
#include <cstdint>
#include <cstddef>

typedef __attribute__((ext_vector_type(4))) float f4;
typedef __attribute__((ext_vector_type(8))) short bf16x8;
typedef __attribute__((ext_vector_type(8))) unsigned short u16x8;

// ---------------- helpers ----------------
__device__ __forceinline__ unsigned short f2bf(float x) {
    unsigned u = __float_as_uint(x);
    u += 0x7fffu + ((u >> 16) & 1u);
    return (unsigned short)(u >> 16);
}
__device__ __forceinline__ float bf2f(unsigned short h) {
    return __uint_as_float(((unsigned)h) << 16);
}
__device__ __forceinline__ float fast_exp2(float x) { return __builtin_amdgcn_exp2f(x); }
__device__ __forceinline__ float fast_log2(float x) { return __builtin_amdgcn_logf(x); }
__device__ __forceinline__ void gll16(const void* g, void* l) {
    __builtin_amdgcn_global_load_lds(
        (const __attribute__((address_space(1))) unsigned int*)g,
        (__attribute__((address_space(3))) unsigned int*)l, 16, 0, 0);
}
__device__ __forceinline__ f4 mfma16(bf16x8 a, bf16x8 b, f4 c) {
    return __builtin_amdgcn_mfma_f32_16x16x32_bf16(a, b, c, 0, 0, 0);
}

// ---------------- weight prep: W[K][N] fp32 -> W^T[N][K] bf16 ----------------
// qkv weights: hi only. Wo: hi + lo (guards the tight `out` threshold).
__global__ __launch_bounds__(256)
void prep_w_kernel(const float* __restrict__ Wq, const float* __restrict__ Wk,
                   const float* __restrict__ Wv, const float* __restrict__ Wo,
                   unsigned short* __restrict__ wt_qkv, unsigned short* __restrict__ wt_o)
{
    const int w = blockIdx.z;
    const float* W = w == 0 ? Wq : (w == 1 ? Wk : (w == 2 ? Wv : Wo));
    unsigned short* hi = (w < 3) ? wt_qkv + (size_t)w * 1048576 : wt_o;
    unsigned short* lo = wt_o + 1048576;     // only used when w==3

    const int kb = blockIdx.x << 6, nb = blockIdx.y << 6;
    __shared__ float T[64][68];
    const int tid = threadIdx.x;
    {
        const int r = tid >> 2, c0 = (tid & 3) << 4;
        const float* src = W + (size_t)(kb + r) * 1024 + nb + c0;
        *(f4*)&T[r][c0 + 0]  = *(const f4*)(src + 0);
        *(f4*)&T[r][c0 + 4]  = *(const f4*)(src + 4);
        *(f4*)&T[r][c0 + 8]  = *(const f4*)(src + 8);
        *(f4*)&T[r][c0 + 12] = *(const f4*)(src + 12);
    }
    __syncthreads();
    {
        const int n = tid & 63, ks = (tid >> 6) << 4;
        unsigned short vh[16], vl[16];
        #pragma unroll
        for (int j = 0; j < 16; ++j) {
            const float x = T[ks + j][n];
            const unsigned short h = f2bf(x);
            vh[j] = h;
            vl[j] = f2bf(x - bf2f(h));
        }
        const size_t dst = (size_t)(nb + n) * 1024 + kb + ks;
        *(u16x8*)(hi + dst)     = *(u16x8*)&vh[0];
        *(u16x8*)(hi + dst + 8) = *(u16x8*)&vh[8];
        if (w == 3) {
            *(u16x8*)(lo + dst)     = *(u16x8*)&vl[0];
            *(u16x8*)(lo + dst + 8) = *(u16x8*)&vl[8];
        }
    }
}

// ---------------- activation prep: q/k/v fp32 -> bf16 (hi only) ----------------
__global__ __launch_bounds__(256)
void prep_a_kernel(const float* __restrict__ q, const float* __restrict__ k,
                   const float* __restrict__ v, unsigned short* __restrict__ a_hi)
{
    const int gid = blockIdx.x * 256 + threadIdx.x;
    const int z = gid >> 18;
    const int rem = gid & 262143;
    const float* src = z == 0 ? q : (z == 1 ? k : v);
    const size_t off = (size_t)rem << 4;
    const float* s = src + off;
    unsigned short* hi = a_hi + ((size_t)z << 22) + off;
    float xs[16];
    *(f4*)&xs[0]  = *(const f4*)(s + 0);
    *(f4*)&xs[4]  = *(const f4*)(s + 4);
    *(f4*)&xs[8]  = *(const f4*)(s + 8);
    *(f4*)&xs[12] = *(const f4*)(s + 12);
    unsigned short hv[16];
    #pragma unroll
    for (int j = 0; j < 16; ++j) hv[j] = f2bf(xs[j]);
    *(u16x8*)(hi + 0) = *(u16x8*)&hv[0];
    *(u16x8*)(hi + 8) = *(u16x8*)&hv[8];
}

// ---------------- 1-term 128x128 GEMM (plain bf16), BK=64, 32 KB LDS ----------------
// C[4096][1024] = A @ W^T' + bias -> head-split bf16 out.
__global__ __launch_bounds__(256)
void qkv_gemm_kernel(const unsigned short* __restrict__ a_hi,
                     const unsigned short* __restrict__ wt_qkv,
                     const float* __restrict__ bq, const float* __restrict__ bk,
                     const float* __restrict__ bv,
                     unsigned short* __restrict__ q_hi, unsigned short* __restrict__ k_hi,
                     unsigned short* __restrict__ v_hi)
{
    __shared__ __align__(16) unsigned char lds[32768];
    unsigned char* As = lds;            // [128 rows][128B k], swz (r&7)
    unsigned char* Bs = lds + 16384;

    const int f = blockIdx.x;                     // 768, %8==0 -> bijective XCD swizzle
    const int id2 = (f & 7) * 96 + (f >> 3);
    const int z = id2 >> 8;
    const int rem = id2 & 255;
    const int bn = rem >> 5, bm = rem & 31;

    const unsigned short* AH = a_hi + ((size_t)z << 22);
    const unsigned short* WH = wt_qkv + (size_t)z * 1048576;
    const float* bias = z == 0 ? bq : (z == 1 ? bk : bv);
    unsigned short* ohi = z == 0 ? q_hi : (z == 1 ? k_hi : v_hi);

    const int tid = threadIdx.x, lane = tid & 63, wave = tid >> 6;
    const int wm = wave >> 1, wn = wave & 1;
    const int cx = lane & 15, lg = lane >> 4;
    const int l3 = lane >> 3, p3 = lane & 7;
    const int m0 = bm << 7, n0 = bn << 7;

    f4 acc[4][4];
    #pragma unroll
    for (int i = 0; i < 4; ++i)
        #pragma unroll
        for (int j = 0; j < 4; ++j) acc[i][j] = (f4){0.f, 0.f, 0.f, 0.f};

    #pragma unroll 1
    for (int k0 = 0; k0 < 1024; k0 += 64) {
        __syncthreads();
        #pragma unroll
        for (int c = 0; c < 4; ++c) {
            const int cb = (c << 2) + wave;          // 0..15, 8 rows each
            const int row = (cb << 3) + l3;          // 0..127
            const int lgx = p3 ^ (row & 7);
            gll16(AH + (size_t)(m0 + row) * 1024 + k0 + (lgx << 3),
                  As + (cb << 10) + (lane << 4));
            gll16(WH + (size_t)(n0 + row) * 1024 + k0 + (lgx << 3),
                  Bs + (cb << 10) + (lane << 4));
        }
        __syncthreads();
        #pragma unroll
        for (int ks = 0; ks < 2; ++ks) {
            bf16x8 ah[4], bh[4];
            #pragma unroll
            for (int t = 0; t < 4; ++t) {
                const int r = (wm << 6) + (t << 4) + cx;
                ah[t] = *(const bf16x8*)(As + r * 128 + (((((ks << 2) + lg)) ^ (r & 7)) << 4));
                const int n = (wn << 6) + (t << 4) + cx;
                bh[t] = *(const bf16x8*)(Bs + n * 128 + (((((ks << 2) + lg)) ^ (n & 7)) << 4));
            }
            #pragma unroll
            for (int i = 0; i < 4; ++i)
                #pragma unroll
                for (int j = 0; j < 4; ++j)
                    acc[i][j] = mfma16(ah[i], bh[j], acc[i][j]);
        }
    }

    float bv4[4];
    #pragma unroll
    for (int j = 0; j < 4; ++j) bv4[j] = bias[n0 + (wn << 6) + (j << 4) + cx];

    #pragma unroll
    for (int i = 0; i < 4; ++i)
        #pragma unroll
        for (int j = 0; j < 4; ++j) {
            const int n = n0 + (wn << 6) + (j << 4) + cx;
            #pragma unroll
            for (int r = 0; r < 4; ++r) {
                const float val = acc[i][j][r] + bv4[j];
                const int m = m0 + (wm << 6) + (i << 4) + (lg << 2) + r;
                const int b = m >> 11, s = m & 2047, hh = n >> 6, d = n & 63;
                ohi[(((size_t)(b * 16 + hh)) * 2048 + s) * 64 + d] = f2bf(val);
            }
        }
}

// ---------------- 3-term 128x128 GEMM (out projection), BK=64 ----------------
__global__ __launch_bounds__(256)
void out_gemm_kernel(const unsigned short* __restrict__ AH, const unsigned short* __restrict__ AL,
                     const unsigned short* __restrict__ wt_o,
                     const float* __restrict__ bo, float* __restrict__ out)
{
    __shared__ __align__(16) unsigned char lds[65536];
    unsigned char* As = lds;            // [128 rows][256B] (hi k0..63 | lo k0..63), swz ((r&7)<<1)
    unsigned char* Bs = lds + 32768;

    const int f = blockIdx.x;                     // 256
    const int id2 = (f & 7) * 32 + (f >> 3);
    const int bn = id2 >> 5, bm = id2 & 31;
    const unsigned short* WH = wt_o;
    const unsigned short* WL = wt_o + 1048576;

    const int tid = threadIdx.x, lane = tid & 63, wave = tid >> 6;
    const int wm = wave >> 1, wn = wave & 1;
    const int cx = lane & 15, lg = lane >> 4;
    const int m0 = bm << 7, n0 = bn << 7;
    const int l4 = lane >> 4, p4 = lane & 15;

    f4 acc[4][4];
    #pragma unroll
    for (int i = 0; i < 4; ++i)
        #pragma unroll
        for (int j = 0; j < 4; ++j) acc[i][j] = (f4){0.f, 0.f, 0.f, 0.f};

    #pragma unroll 1
    for (int k0 = 0; k0 < 1024; k0 += 64) {
        __syncthreads();
        #pragma unroll
        for (int c = 0; c < 8; ++c) {
            const int cb = (c << 2) + wave;
            const int row = (cb << 2) + l4;
            const int lgx = p4 ^ ((row & 7) << 1);
            const unsigned short* sa = (lgx < 8 ? AH : AL)
                + (size_t)(m0 + row) * 1024 + k0 + ((lgx & 7) << 3);
            gll16(sa, As + (cb << 10) + (lane << 4));
            const unsigned short* sb = (lgx < 8 ? WH : WL)
                + (size_t)(n0 + row) * 1024 + k0 + ((lgx & 7) << 3);
            gll16(sb, Bs + (cb << 10) + (lane << 4));
        }
        __syncthreads();
        #pragma unroll
        for (int ks = 0; ks < 2; ++ks) {
            bf16x8 ah[4], al[4], bh[4], bl[4];
            #pragma unroll
            for (int t = 0; t < 4; ++t) {
                const int r = (wm << 6) + (t << 4) + cx;
                const int mk = (r & 7) << 1;
                ah[t] = *(const bf16x8*)(As + r * 256 + (((((ks << 2) + lg))     ^ mk) << 4));
                al[t] = *(const bf16x8*)(As + r * 256 + (((((ks << 2) + lg + 8)) ^ mk) << 4));
                const int n = (wn << 6) + (t << 4) + cx;
                const int mkn = (n & 7) << 1;
                bh[t] = *(const bf16x8*)(Bs + n * 256 + (((((ks << 2) + lg))     ^ mkn) << 4));
                bl[t] = *(const bf16x8*)(Bs + n * 256 + (((((ks << 2) + lg + 8)) ^ mkn) << 4));
            }
            #pragma unroll
            for (int i = 0; i < 4; ++i)
                #pragma unroll
                for (int j = 0; j < 4; ++j) {
                    acc[i][j] = mfma16(ah[i], bh[j], acc[i][j]);
                    acc[i][j] = mfma16(ah[i], bl[j], acc[i][j]);
                    acc[i][j] = mfma16(al[i], bh[j], acc[i][j]);
                }
        }
    }

    float bv4[4];
    #pragma unroll
    for (int j = 0; j < 4; ++j) bv4[j] = bo[n0 + (wn << 6) + (j << 4) + cx];

    #pragma unroll
    for (int i = 0; i < 4; ++i)
        #pragma unroll
        for (int j = 0; j < 4; ++j) {
            const int n = n0 + (wn << 6) + (j << 4) + cx;
            #pragma unroll
            for (int r = 0; r < 4; ++r) {
                const int m = m0 + (wm << 6) + (i << 4) + (lg << 2) + r;
                out[(size_t)m * 1024 + n] = acc[i][j][r] + bv4[j];
            }
        }
}

// ---------------- fused attention: 1-term QK, fixed-shift softmax, 32 KB LDS ----------------
__global__ __launch_bounds__(256, 4)
void attn_kernel(const unsigned short* __restrict__ q_hi, const unsigned short* __restrict__ k_hi,
                 const unsigned short* __restrict__ v_hi, const float* __restrict__ mask,
                 float* __restrict__ attn,
                 unsigned short* __restrict__ ctx_hi, unsigned short* __restrict__ ctx_lo)
{
    __shared__ __align__(16) unsigned char lds[32768];
    unsigned char* K1 = lds;             // 2 x 8KB: K [64 rows][128B], swz (r&7)
    unsigned char* Vs = lds + 16384;     //     8KB: V^T [64 d][128B s], swz (d&7)
    unsigned char* Ps = lds + 24576;     //     8KB: P [64 q][128B k] (Q staged here at prologue)

    const int f = blockIdx.x;                       // 1024, %8==0 bijective
    const int swz = (f & 7) * 128 + (f >> 3);
    const int bh = swz >> 5;
    const int q0 = (swz & 31) << 6;
    const int b = bh >> 4, h = bh & 15;
    const int tid = threadIdx.x, lane = tid & 63, wave = tid >> 6;
    const int cx = lane & 15, lg = lane >> 4;
    const int l3 = lane >> 3, p3 = lane & 7;
    const size_t base = (size_t)bh * 131072;
    const float* mg = mask + (size_t)b * 2048;

    constexpr float C2   = 0.18033688011112042f;     // 0.125 * log2(e)
    constexpr float M2   = -1.4426950408889634e9f;   // -1e9 * log2(e)
    constexpr float MFIX = 4.0f;                     // fixed softmax shift (log2 domain)

    // ---- prologue: Q -> Ps, K tile0 -> K1[0] ----
    #pragma unroll
    for (int c = 0; c < 2; ++c) {
        const int cb = (c << 2) + wave;
        const int row = (cb << 3) + l3;
        const int lgx = p3 ^ (row & 7);
        gll16(q_hi + base + (size_t)(q0 + row) * 64 + (lgx << 3),
              Ps + (cb << 10) + (lane << 4));
        gll16(k_hi + base + (size_t)row * 64 + (lgx << 3),
              K1 + (cb << 10) + (lane << 4));
    }
    __syncthreads();

    bf16x8 qa_h[2];
    {
        const int r = (wave << 4) + cx;
        const int mk = r & 7;
        #pragma unroll
        for (int ks = 0; ks < 2; ++ks)
            qa_h[ks] = *(const bf16x8*)(Ps + r * 128 + (((((ks << 2) + lg)) ^ mk) << 4));
    }

    // ---- pass 1: row sums (fixed shift, no shuffles in loop) ----
    float l_loc[4] = {0.f, 0.f, 0.f, 0.f};
    #pragma unroll 1
    for (int t = 0; t < 32; ++t) {
        const int p = t & 1;
        if (t < 31) {
            const int k0n = (t + 1) << 6;
            #pragma unroll
            for (int c = 0; c < 2; ++c) {
                const int cb = (c << 2) + wave;
                const int row = (cb << 3) + l3;
                const int lgx = p3 ^ (row & 7);
                gll16(k_hi + base + (size_t)(k0n + row) * 64 + (lgx << 3),
                      K1 + ((p ^ 1) << 13) + (cb << 10) + (lane << 4));
            }
        }
        const unsigned char* Kc = K1 + (p << 13);
        f4 s[4];
        #pragma unroll
        for (int nt = 0; nt < 4; ++nt) s[nt] = (f4){0.f, 0.f, 0.f, 0.f};
        #pragma unroll
        for (int nt = 0; nt < 4; ++nt) {
            const int kr = (nt << 4) + cx;
            const int mk = kr & 7;
            #pragma unroll
            for (int ks = 0; ks < 2; ++ks) {
                const bf16x8 kb = *(const bf16x8*)(Kc + kr * 128 + (((((ks << 2) + lg)) ^ mk) << 4));
                s[nt] = mfma16(qa_h[ks], kb, s[nt]);
            }
        }
        const int k0 = t << 6;
        float ml[4];
        #pragma unroll
        for (int nt = 0; nt < 4; ++nt) ml[nt] = fmaf(mg[k0 + (nt << 4) + cx], M2, -MFIX);
        #pragma unroll
        for (int r = 0; r < 4; ++r) {
            l_loc[r] += fast_exp2(fmaf(s[0][r], C2, ml[0]))
                      + fast_exp2(fmaf(s[1][r], C2, ml[1]))
                      + fast_exp2(fmaf(s[2][r], C2, ml[2]))
                      + fast_exp2(fmaf(s[3][r], C2, ml[3]));
        }
        __syncthreads();
    }

    float ofs[4];
    #pragma unroll
    for (int r = 0; r < 4; ++r) {
        float ss = l_loc[r];
        ss += __shfl_xor(ss, 1);
        ss += __shfl_xor(ss, 2);
        ss += __shfl_xor(ss, 4);
        ss += __shfl_xor(ss, 8);
        ofs[r] = MFIX + fast_log2(ss);   // P = exp2(lgt - ofs)
    }

    // ---- pass 2 prologue: K tile0 -> K1[0], V tile0 -> regs ----
    #pragma unroll
    for (int c = 0; c < 2; ++c) {
        const int cb = (c << 2) + wave;
        const int row = (cb << 3) + l3;
        const int lgx = p3 ^ (row & 7);
        gll16(k_hi + base + (size_t)row * 64 + (lgx << 3),
              K1 + (cb << 10) + (lane << 4));
    }
    u16x8 vr0 = *(const u16x8*)(v_hi + base + (size_t)lane * 64 + (wave << 4));
    u16x8 vr1 = *(const u16x8*)(v_hi + base + (size_t)lane * 64 + (wave << 4) + 8);
    __syncthreads();

    f4 cacc[4];
    #pragma unroll
    for (int nt = 0; nt < 4; ++nt) cacc[nt] = (f4){0.f, 0.f, 0.f, 0.f};

    #pragma unroll 1
    for (int t = 0; t < 32; ++t) {
        const int k0 = t << 6;
        const int p = t & 1;
        // [A] prefetch next K tile
        if (t < 31) {
            #pragma unroll
            for (int c = 0; c < 2; ++c) {
                const int cb = (c << 2) + wave;
                const int row = (cb << 3) + l3;
                const int lgx = p3 ^ (row & 7);
                gll16(k_hi + base + (size_t)(k0 + 64 + row) * 64 + (lgx << 3),
                      K1 + ((p ^ 1) << 13) + (cb << 10) + (lane << 4));
            }
        }
        // [A2] next V -> regs
        u16x8 vn0 = vr0, vn1 = vr1;
        if (t < 31) {
            vn0 = *(const u16x8*)(v_hi + base + (size_t)(k0 + 64 + lane) * 64 + (wave << 4));
            vn1 = *(const u16x8*)(v_hi + base + (size_t)(k0 + 64 + lane) * 64 + (wave << 4) + 8);
        }
        // [B] QK^T 1-term on K1[p]
        const unsigned char* Kc = K1 + (p << 13);
        f4 s[4];
        #pragma unroll
        for (int nt = 0; nt < 4; ++nt) s[nt] = (f4){0.f, 0.f, 0.f, 0.f};
        #pragma unroll
        for (int nt = 0; nt < 4; ++nt) {
            const int kr = (nt << 4) + cx;
            const int mk = kr & 7;
            #pragma unroll
            for (int ks = 0; ks < 2; ++ks) {
                const bf16x8 kb = *(const bf16x8*)(Kc + kr * 128 + (((((ks << 2) + lg)) ^ mk) << 4));
                s[nt] = mfma16(qa_h[ks], kb, s[nt]);
            }
        }
        // [C] V^T stage into Vs (single buffer; prev reads fenced by last barrier)
        {
            const int slot = lane >> 3, sb = (lane & 7) << 1;
            #pragma unroll
            for (int j = 0; j < 8; ++j) {
                const int d = (wave << 4) + j;
                *(unsigned short*)(Vs + d * 128 + ((slot ^ (d & 7)) << 4) + sb) = (unsigned short)vr0[j];
                const int d2 = d + 8;
                *(unsigned short*)(Vs + d2 * 128 + ((slot ^ (d2 & 7)) << 4) + sb) = (unsigned short)vr1[j];
            }
        }
        // [E] probabilities: attn store + Ps write
        float mk2[4];
        #pragma unroll
        for (int nt = 0; nt < 4; ++nt) mk2[nt] = mg[k0 + (nt << 4) + cx] * M2;
        #pragma unroll
        for (int nt = 0; nt < 4; ++nt) {
            #pragma unroll
            for (int r = 0; r < 4; ++r) {
                const float pr = fast_exp2(fmaf(s[nt][r], C2, mk2[nt]) - ofs[r]);
                const int qrow = (wave << 4) + (lg << 2) + r;
                attn[((size_t)bh * 2048 + q0 + qrow) * 2048 + k0 + (nt << 4) + cx] = pr;
                const int col = (nt << 4) + cx;
                *(unsigned short*)(Ps + qrow * 128 + (((col >> 3) ^ (qrow & 7)) << 4)
                                   + ((col & 7) << 1)) = f2bf(pr);
            }
        }
        __syncthreads();
        // [G] PV
        {
            const int qr = (wave << 4) + cx;
            #pragma unroll
            for (int ks = 0; ks < 2; ++ks) {
                const bf16x8 pa = *(const bf16x8*)(Ps + qr * 128 + (((((ks << 2) + lg)) ^ (qr & 7)) << 4));
                #pragma unroll
                for (int nt = 0; nt < 4; ++nt) {
                    const int dr = (nt << 4) + cx;
                    const bf16x8 vb = *(const bf16x8*)(Vs + dr * 128 + (((((ks << 2) + lg)) ^ (dr & 7)) << 4));
                    cacc[nt] = mfma16(pa, vb, cacc[nt]);
                }
            }
        }
        __syncthreads();
        vr0 = vn0; vr1 = vn1;
    }

    // ---- ctx out (bf16 hi/lo, feeds out_gemm directly) ----
    #pragma unroll
    for (int nt = 0; nt < 4; ++nt)
        #pragma unroll
        for (int r = 0; r < 4; ++r) {
            const int srow = q0 + (wave << 4) + (lg << 2) + r;
            const int d = (h << 6) + (nt << 4) + cx;
            const size_t cidx = ((size_t)b * 2048 + srow) * 1024 + d;
            const float val = cacc[nt][r];
            const unsigned short hv = f2bf(val);
            ctx_hi[cidx] = hv;
            ctx_lo[cidx] = f2bf(val - bf2f(hv));
        }
}

// ---------------- launcher ----------------
extern "C" void kernel_launch(void* const* d_in, const int* in_sizes, int n_in,
                              void* d_out, int out_size, void* d_ws, size_t ws_size,
                              hipStream_t stream)
{
    const float* v_in = (const float*)d_in[0];
    const float* k_in = (const float*)d_in[1];
    const float* q_in = (const float*)d_in[2];
    const float* mask = (const float*)d_in[3];
    const float* Wq = (const float*)d_in[4];
    const float* bq = (const float*)d_in[5];
    const float* Wk = (const float*)d_in[6];
    const float* bk = (const float*)d_in[7];
    const float* Wv = (const float*)d_in[8];
    const float* bv = (const float*)d_in[9];
    const float* Wo = (const float*)d_in[10];
    const float* bo = (const float*)d_in[11];

    float* out  = (float*)d_out;                    // [2,2048,1024]
    float* attn = out + (size_t)4194304;            // [2,16,2048,2048] = 512 MB

    unsigned char* ws = (unsigned char*)d_ws;       // 44 MB used
    unsigned short* wt_o   = (unsigned short*)(ws);                         // 4 MB hi|lo
    unsigned short* q_hi   = (unsigned short*)(ws + (size_t)(4)  * 1048576);
    unsigned short* k_hi   = (unsigned short*)(ws + (size_t)(12) * 1048576);
    unsigned short* v_hi   = (unsigned short*)(ws + (size_t)(20) * 1048576);
    unsigned short* ctx_hi = (unsigned short*)(ws + (size_t)(28) * 1048576);
    unsigned short* ctx_lo = (unsigned short*)(ws + (size_t)(36) * 1048576);

    // dead scratch inside the attn output region (overwritten by attn_kernel later)
    unsigned short* a_hi   = (unsigned short*)(attn + (size_t)60  * 1048576);  // 24 MB
    unsigned short* wt_qkv = (unsigned short*)(attn + (size_t)100 * 1048576);  // 6 MB

    prep_w_kernel<<<dim3(16, 16, 4), 256, 0, stream>>>(Wq, Wk, Wv, Wo, wt_qkv, wt_o);
    prep_a_kernel<<<3072, 256, 0, stream>>>(q_in, k_in, v_in, a_hi);
    qkv_gemm_kernel<<<768, 256, 0, stream>>>(a_hi, wt_qkv, bq, bk, bv,
                                             q_hi, k_hi, v_hi);
    attn_kernel<<<1024, 256, 0, stream>>>(q_hi, k_hi, v_hi, mask,
                                          attn, ctx_hi, ctx_lo);
    out_gemm_kernel<<<256, 256, 0, stream>>>(ctx_hi, ctx_lo, wt_o, bo, out);
}

// Round 8
// 299.006 us; speedup vs baseline: 1.4344x; 1.0050x over previous
//
#include <hip/hip_runtime.h>
#include <cstdint>
#include <cstddef>

typedef __attribute__((ext_vector_type(4))) float f4;
typedef __attribute__((ext_vector_type(8))) short bf16x8;
typedef __attribute__((ext_vector_type(8))) unsigned short u16x8;
typedef unsigned long long u64;

// ---------------- helpers ----------------
__device__ __forceinline__ unsigned short f2bf(float x) {
    unsigned u = __float_as_uint(x);
    u += 0x7fffu + ((u >> 16) & 1u);
    return (unsigned short)(u >> 16);
}
__device__ __forceinline__ float bf2f(unsigned short h) {
    return __uint_as_float(((unsigned)h) << 16);
}
__device__ __forceinline__ float fast_exp2(float x) { return __builtin_amdgcn_exp2f(x); }
__device__ __forceinline__ float fast_log2(float x) { return __builtin_amdgcn_logf(x); }
__device__ __forceinline__ void gll16(const void* g, void* l) {
    __builtin_amdgcn_global_load_lds(
        (const __attribute__((address_space(1))) unsigned int*)g,
        (__attribute__((address_space(3))) unsigned int*)l, 16, 0, 0);
}
__device__ __forceinline__ f4 mfma16(bf16x8 a, bf16x8 b, f4 c) {
    return __builtin_amdgcn_mfma_f32_16x16x32_bf16(a, b, c, 0, 0, 0);
}

// ---------------- weight prep: W[K][N] fp32 -> W^T[N][K] bf16 (hi only) ----------------
__global__ __launch_bounds__(256)
void prep_w_kernel(const float* __restrict__ Wq, const float* __restrict__ Wk,
                   const float* __restrict__ Wv, const float* __restrict__ Wo,
                   unsigned short* __restrict__ wt)   // 4 x 1048576
{
    const int w = blockIdx.z;
    const float* W = w == 0 ? Wq : (w == 1 ? Wk : (w == 2 ? Wv : Wo));
    unsigned short* hi = wt + (size_t)w * 1048576;

    const int kb = blockIdx.x << 6, nb = blockIdx.y << 6;
    __shared__ float T[64][68];
    const int tid = threadIdx.x;
    {
        const int r = tid >> 2, c0 = (tid & 3) << 4;
        const float* src = W + (size_t)(kb + r) * 1024 + nb + c0;
        *(f4*)&T[r][c0 + 0]  = *(const f4*)(src + 0);
        *(f4*)&T[r][c0 + 4]  = *(const f4*)(src + 4);
        *(f4*)&T[r][c0 + 8]  = *(const f4*)(src + 8);
        *(f4*)&T[r][c0 + 12] = *(const f4*)(src + 12);
    }
    __syncthreads();
    {
        const int n = tid & 63, ks = (tid >> 6) << 4;
        unsigned short vh[16];
        #pragma unroll
        for (int j = 0; j < 16; ++j) vh[j] = f2bf(T[ks + j][n]);
        const size_t dst = (size_t)(nb + n) * 1024 + kb + ks;
        *(u16x8*)(hi + dst)     = *(u16x8*)&vh[0];
        *(u16x8*)(hi + dst + 8) = *(u16x8*)&vh[8];
    }
}

// ---------------- activation prep: q/k/v fp32 -> bf16 ----------------
__global__ __launch_bounds__(256)
void prep_a_kernel(const float* __restrict__ q, const float* __restrict__ k,
                   const float* __restrict__ v, unsigned short* __restrict__ a_hi)
{
    const int gid = blockIdx.x * 256 + threadIdx.x;
    const int z = gid >> 18;
    const int rem = gid & 262143;
    const float* src = z == 0 ? q : (z == 1 ? k : v);
    const size_t off = (size_t)rem << 4;
    const float* s = src + off;
    unsigned short* hi = a_hi + ((size_t)z << 22) + off;
    float xs[16];
    *(f4*)&xs[0]  = *(const f4*)(s + 0);
    *(f4*)&xs[4]  = *(const f4*)(s + 4);
    *(f4*)&xs[8]  = *(const f4*)(s + 8);
    *(f4*)&xs[12] = *(const f4*)(s + 12);
    unsigned short hv[16];
    #pragma unroll
    for (int j = 0; j < 16; ++j) hv[j] = f2bf(xs[j]);
    *(u16x8*)(hi + 0) = *(u16x8*)&hv[0];
    *(u16x8*)(hi + 8) = *(u16x8*)&hv[8];
}

// ---------------- 1-term 128x128 GEMM core (plain bf16), BK=64, 32 KB LDS ----------------
// mode 1: head-split bf16 out; mode 2: fp32 [m][n] out.
__device__ __forceinline__ void gemm1_core(
    const unsigned short* __restrict__ AH, const unsigned short* __restrict__ WH,
    const float* __restrict__ bias, int bm, int bn, int mode,
    unsigned short* __restrict__ o_hi, float* __restrict__ o_f32, unsigned char* lds)
{
    unsigned char* As = lds;            // [128 rows][128B k], swz (r&7)
    unsigned char* Bs = lds + 16384;

    const int tid = threadIdx.x, lane = tid & 63, wave = tid >> 6;
    const int wm = wave >> 1, wn = wave & 1;
    const int cx = lane & 15, lg = lane >> 4;
    const int l3 = lane >> 3, p3 = lane & 7;
    const int m0 = bm << 7, n0 = bn << 7;

    f4 acc[4][4];
    #pragma unroll
    for (int i = 0; i < 4; ++i)
        #pragma unroll
        for (int j = 0; j < 4; ++j) acc[i][j] = (f4){0.f, 0.f, 0.f, 0.f};

    #pragma unroll 1
    for (int k0 = 0; k0 < 1024; k0 += 64) {
        __syncthreads();
        #pragma unroll
        for (int c = 0; c < 4; ++c) {
            const int cb = (c << 2) + wave;
            const int row = (cb << 3) + l3;
            const int lgx = p3 ^ (row & 7);
            gll16(AH + (size_t)(m0 + row) * 1024 + k0 + (lgx << 3),
                  As + (cb << 10) + (lane << 4));
            gll16(WH + (size_t)(n0 + row) * 1024 + k0 + (lgx << 3),
                  Bs + (cb << 10) + (lane << 4));
        }
        __syncthreads();
        #pragma unroll
        for (int ks = 0; ks < 2; ++ks) {
            bf16x8 ah[4], bh[4];
            #pragma unroll
            for (int t = 0; t < 4; ++t) {
                const int r = (wm << 6) + (t << 4) + cx;
                ah[t] = *(const bf16x8*)(As + r * 128 + (((((ks << 2) + lg)) ^ (r & 7)) << 4));
                const int n = (wn << 6) + (t << 4) + cx;
                bh[t] = *(const bf16x8*)(Bs + n * 128 + (((((ks << 2) + lg)) ^ (n & 7)) << 4));
            }
            #pragma unroll
            for (int i = 0; i < 4; ++i)
                #pragma unroll
                for (int j = 0; j < 4; ++j)
                    acc[i][j] = mfma16(ah[i], bh[j], acc[i][j]);
        }
    }

    float bv4[4];
    #pragma unroll
    for (int j = 0; j < 4; ++j) bv4[j] = bias[n0 + (wn << 6) + (j << 4) + cx];

    #pragma unroll
    for (int i = 0; i < 4; ++i)
        #pragma unroll
        for (int j = 0; j < 4; ++j) {
            const int n = n0 + (wn << 6) + (j << 4) + cx;
            #pragma unroll
            for (int r = 0; r < 4; ++r) {
                const float val = acc[i][j][r] + bv4[j];
                const int m = m0 + (wm << 6) + (i << 4) + (lg << 2) + r;
                if (mode == 2) {
                    o_f32[(size_t)m * 1024 + n] = val;
                } else {
                    const int b = m >> 11, s = m & 2047, hh = n >> 6, d = n & 63;
                    o_hi[(((size_t)(b * 16 + hh)) * 2048 + s) * 64 + d] = f2bf(val);
                }
            }
        }
}

__global__ __launch_bounds__(256)
void qkv_gemm_kernel(const unsigned short* __restrict__ a_hi,
                     const unsigned short* __restrict__ wt,
                     const float* __restrict__ bq, const float* __restrict__ bk,
                     const float* __restrict__ bv,
                     unsigned short* __restrict__ q_hi, unsigned short* __restrict__ k_hi,
                     unsigned short* __restrict__ v_hi)
{
    __shared__ __align__(16) unsigned char lds[32768];
    const int f = blockIdx.x;                     // 768, %8==0 -> bijective XCD swizzle
    const int id2 = (f & 7) * 96 + (f >> 3);
    const int z = id2 >> 8;
    const int rem = id2 & 255;
    const int bn = rem >> 5, bm = rem & 31;
    const unsigned short* AH = a_hi + ((size_t)z << 22);
    const unsigned short* WH = wt + (size_t)z * 1048576;
    const float* bias = z == 0 ? bq : (z == 1 ? bk : bv);
    unsigned short* ohi = z == 0 ? q_hi : (z == 1 ? k_hi : v_hi);
    gemm1_core(AH, WH, bias, bm, bn, 1, ohi, nullptr, lds);
}

__global__ __launch_bounds__(256)
void out_gemm_kernel(const unsigned short* __restrict__ ctx_hi,
                     const unsigned short* __restrict__ wt_o,
                     const float* __restrict__ bo, float* __restrict__ out)
{
    __shared__ __align__(16) unsigned char lds[32768];
    const int f = blockIdx.x;                     // 256
    const int id2 = (f & 7) * 32 + (f >> 3);
    const int bn = id2 >> 5, bm = id2 & 31;
    gemm1_core(ctx_hi, wt_o, bo, bm, bn, 2, nullptr, out, lds);
}

// ---------------- fused attention: swapped QK, reg-staged V^T, 1 barrier/tile ----------------
__global__ __launch_bounds__(256, 3)
void attn_kernel(const unsigned short* __restrict__ q_hi, const unsigned short* __restrict__ k_hi,
                 const unsigned short* __restrict__ v_hi, const float* __restrict__ mask,
                 float* __restrict__ attn, unsigned short* __restrict__ ctx_hi)
{
    __shared__ __align__(16) unsigned char lds[49152];
    unsigned char* K1 = lds;             // 2 x 8KB: K [64 rows][128B d], swz (r&7)
    unsigned char* Vs = lds + 16384;     // 2 x 8KB: V^T [64 d][128B s], swz (d&7)
    unsigned char* Ps = lds + 32768;     //     8KB: Q rows at prologue, then P [64 q][128B k]
    float*         ML = (float*)(lds + 40960);   // 8KB: ml[k] = mask[k]*M2 - MFIX

    const int f = blockIdx.x;                       // 1024, %8==0 bijective
    const int swzf = (f & 7) * 128 + (f >> 3);
    const int bh = swzf >> 5;
    const int q0 = (swzf & 31) << 6;
    const int b = bh >> 4, h = bh & 15;
    const int tid = threadIdx.x, lane = tid & 63, wave = tid >> 6;
    const int cx = lane & 15, lg = lane >> 4;
    const int l3 = lane >> 3, p3 = lane & 7;
    const size_t base = (size_t)bh * 131072;
    const float* mg = mask + (size_t)b * 2048;

    constexpr float C2   = 0.18033688011112042f;     // 0.125 * log2(e)
    constexpr float M2   = -1.4426950408889634e9f;   // -1e9 * log2(e)
    constexpr float MFIX = 4.0f;

    // ---- prologue: ml table, Q -> Ps area, K tile0 -> K1[0], V tile0 -> Vs[0] ----
    {
        const int i0 = tid << 3;
        f4 mv0 = *(const f4*)(mg + i0);
        f4 mv1 = *(const f4*)(mg + i0 + 4);
        f4 w0, w1;
        #pragma unroll
        for (int j = 0; j < 4; ++j) { w0[j] = fmaf(mv0[j], M2, -MFIX); w1[j] = fmaf(mv1[j], M2, -MFIX); }
        *(f4*)(ML + i0) = w0;
        *(f4*)(ML + i0 + 4) = w1;
    }
    #pragma unroll
    for (int c = 0; c < 2; ++c) {
        const int cb = (c << 2) + wave;
        const int row = (cb << 3) + l3;
        const int lgx = p3 ^ (row & 7);
        gll16(q_hi + base + (size_t)(q0 + row) * 64 + (lgx << 3),
              Ps + (cb << 10) + (lane << 4));
        gll16(k_hi + base + (size_t)row * 64 + (lgx << 3),
              K1 + (cb << 10) + (lane << 4));
    }
    {   // V tile0 -> regs -> Vs[0] transposed ([d][s], swz (d&7))
        u16x8 v0 = *(const u16x8*)(v_hi + base + (size_t)lane * 64 + (wave << 4));
        u16x8 v1 = *(const u16x8*)(v_hi + base + (size_t)lane * 64 + (wave << 4) + 8);
        const int slot = lane >> 3, sb = (lane & 7) << 1;
        #pragma unroll
        for (int j = 0; j < 8; ++j) {
            const int d = (wave << 4) + j;
            *(unsigned short*)(Vs + d * 128 + ((slot ^ (d & 7)) << 4) + sb) = (unsigned short)v0[j];
            const int d2 = d + 8;
            *(unsigned short*)(Vs + d2 * 128 + ((slot ^ (d2 & 7)) << 4) + sb) = (unsigned short)v1[j];
        }
    }
    __syncthreads();

    bf16x8 qb[2];
    {
        const int r = (wave << 4) + cx;
        const int mk = r & 7;
        #pragma unroll
        for (int ks = 0; ks < 2; ++ks)
            qb[ks] = *(const bf16x8*)(Ps + r * 128 + (((((ks << 2) + lg)) ^ mk) << 4));
    }

    // ---- pass 1: row sums. lane owns q = wave*16+cx; k = nt*16+lg*4+r ----
    float l_loc = 0.f;
    #pragma unroll 1
    for (int t = 0; t < 32; ++t) {
        const int p = t & 1;
        const int k0 = t << 6;
        if (t < 31) {
            #pragma unroll
            for (int c = 0; c < 2; ++c) {
                const int cb = (c << 2) + wave;
                const int row = (cb << 3) + l3;
                const int lgx = p3 ^ (row & 7);
                gll16(k_hi + base + (size_t)(k0 + 64 + row) * 64 + (lgx << 3),
                      K1 + ((p ^ 1) << 13) + (cb << 10) + (lane << 4));
            }
        }
        const unsigned char* Kc = K1 + (p << 13);
        #pragma unroll
        for (int nt = 0; nt < 4; ++nt) {
            const int kr = (nt << 4) + cx;
            const int mk = kr & 7;
            f4 s = (f4){0.f, 0.f, 0.f, 0.f};
            #pragma unroll
            for (int ks = 0; ks < 2; ++ks) {
                const bf16x8 kb = *(const bf16x8*)(Kc + kr * 128 + (((((ks << 2) + lg)) ^ mk) << 4));
                s = mfma16(kb, qb[ks], s);
            }
            const f4 mlv = *(const f4*)(ML + k0 + (nt << 4) + (lg << 2));
            l_loc += fast_exp2(fmaf(s[0], C2, mlv[0]))
                   + fast_exp2(fmaf(s[1], C2, mlv[1]))
                   + fast_exp2(fmaf(s[2], C2, mlv[2]))
                   + fast_exp2(fmaf(s[3], C2, mlv[3]));
        }
        asm volatile("s_waitcnt vmcnt(0) lgkmcnt(0)" ::: "memory");
        __builtin_amdgcn_s_barrier();
    }
    float ss = l_loc;
    ss += __shfl_xor(ss, 16);
    ss += __shfl_xor(ss, 32);
    const float ofs2 = fast_log2(ss);    // MFIX folded into ML and cancels exactly

    // ---- pass 2 prologue: K tile0 -> K1[0], V tile0 -> Vs[0] ----
    #pragma unroll
    for (int c = 0; c < 2; ++c) {
        const int cb = (c << 2) + wave;
        const int row = (cb << 3) + l3;
        const int lgx = p3 ^ (row & 7);
        gll16(k_hi + base + (size_t)row * 64 + (lgx << 3),
              K1 + (cb << 10) + (lane << 4));
    }
    {
        u16x8 v0 = *(const u16x8*)(v_hi + base + (size_t)lane * 64 + (wave << 4));
        u16x8 v1 = *(const u16x8*)(v_hi + base + (size_t)lane * 64 + (wave << 4) + 8);
        const int slot = lane >> 3, sb = (lane & 7) << 1;
        #pragma unroll
        for (int j = 0; j < 8; ++j) {
            const int d = (wave << 4) + j;
            *(unsigned short*)(Vs + d * 128 + ((slot ^ (d & 7)) << 4) + sb) = (unsigned short)v0[j];
            const int d2 = d + 8;
            *(unsigned short*)(Vs + d2 * 128 + ((slot ^ (d2 & 7)) << 4) + sb) = (unsigned short)v1[j];
        }
    }
    __syncthreads();

    f4 cacc[4];
    #pragma unroll
    for (int nt = 0; nt < 4; ++nt) cacc[nt] = (f4){0.f, 0.f, 0.f, 0.f};

    float* arow = attn + ((size_t)bh * 2048 + q0 + (wave << 4) + cx) * 2048;
    const unsigned psSwz = (unsigned)((cx & 7) << 4);

    #pragma unroll 1
    for (int t = 0; t < 32; ++t) {
        const int p = t & 1;
        const int k0 = t << 6;
        // [A] stage K(t+1) -> K1[p^1]; load V(t+1) -> regs
        u16x8 vn0, vn1;
        if (t < 31) {
            #pragma unroll
            for (int c = 0; c < 2; ++c) {
                const int cb = (c << 2) + wave;
                const int row = (cb << 3) + l3;
                const int lgx = p3 ^ (row & 7);
                gll16(k_hi + base + (size_t)(k0 + 64 + row) * 64 + (lgx << 3),
                      K1 + ((p ^ 1) << 13) + (cb << 10) + (lane << 4));
            }
            vn0 = *(const u16x8*)(v_hi + base + (size_t)(k0 + 64 + lane) * 64 + (wave << 4));
            vn1 = *(const u16x8*)(v_hi + base + (size_t)(k0 + 64 + lane) * 64 + (wave << 4) + 8);
        }
        // [B] swapped QK^T on K1[p]: s[nt][r] = S[k=nt*16+lg*4+r][q=wave*16+cx]
        const unsigned char* Kc = K1 + (p << 13);
        f4 s[4];
        #pragma unroll
        for (int nt = 0; nt < 4; ++nt) {
            const int kr = (nt << 4) + cx;
            const int mk = kr & 7;
            s[nt] = (f4){0.f, 0.f, 0.f, 0.f};
            #pragma unroll
            for (int ks = 0; ks < 2; ++ks) {
                const bf16x8 kb = *(const bf16x8*)(Kc + kr * 128 + (((((ks << 2) + lg)) ^ mk) << 4));
                s[nt] = mfma16(kb, qb[ks], s[nt]);
            }
        }
        // [E] P = exp2(logit - ofs2); vectorized attn store; u64 Ps write (wave-private rows)
        #pragma unroll
        for (int nt = 0; nt < 4; ++nt) {
            const f4 mlv = *(const f4*)(ML + k0 + (nt << 4) + (lg << 2));
            f4 pv;
            #pragma unroll
            for (int r = 0; r < 4; ++r)
                pv[r] = fast_exp2(fmaf(s[nt][r], C2, mlv[r]) - ofs2);
            *(f4*)(arow + k0 + (nt << 4) + (lg << 2)) = pv;
            const unsigned w0 = (unsigned)f2bf(pv[0]) | ((unsigned)f2bf(pv[1]) << 16);
            const unsigned w1 = (unsigned)f2bf(pv[2]) | ((unsigned)f2bf(pv[3]) << 16);
            const u64 packed = (u64)w0 | ((u64)w1 << 32);
            *(u64*)(Ps + (((wave << 4) + cx) * 128) +
                    ((unsigned)((nt << 5) + (lg << 3)) ^ psSwz)) = packed;
        }
        // [C] write V(t+1) regs -> Vs[p^1] transposed
        if (t < 31) {
            unsigned char* Vb = Vs + ((p ^ 1) << 13);
            const int slot = lane >> 3, sb = (lane & 7) << 1;
            #pragma unroll
            for (int j = 0; j < 8; ++j) {
                const int d = (wave << 4) + j;
                *(unsigned short*)(Vb + d * 128 + ((slot ^ (d & 7)) << 4) + sb) = (unsigned short)vn0[j];
                const int d2 = d + 8;
                *(unsigned short*)(Vb + d2 * 128 + ((slot ^ (d2 & 7)) << 4) + sb) = (unsigned short)vn1[j];
            }
        }
        // [G] PV: pa from Ps (same wave, in-order LDS), vb from Vs[p] (staged at t-1)
        #pragma unroll
        for (int ks = 0; ks < 2; ++ks) {
            const bf16x8 pa = *(const bf16x8*)(Ps + (((wave << 4) + cx) * 128) +
                                ((unsigned)((ks << 6) + (lg << 4)) ^ psSwz));
            #pragma unroll
            for (int nt = 0; nt < 4; ++nt) {
                const int dr = (nt << 4) + cx;
                const bf16x8 vb = *(const bf16x8*)(Vs + (p << 13) + dr * 128 +
                                    (((((ks << 2) + lg)) ^ (dr & 7)) << 4));
                cacc[nt] = mfma16(pa, vb, cacc[nt]);
            }
        }
        asm volatile("s_waitcnt vmcnt(4) lgkmcnt(0)" ::: "memory");
        __builtin_amdgcn_s_barrier();
    }

    // ---- ctx out: lane holds q = wave*16+lg*4+r, d = nt*16+cx ----
    #pragma unroll
    for (int nt = 0; nt < 4; ++nt)
        #pragma unroll
        for (int r = 0; r < 4; ++r) {
            const int srow = q0 + (wave << 4) + (lg << 2) + r;
            const int d = (h << 6) + (nt << 4) + cx;
            ctx_hi[((size_t)b * 2048 + srow) * 1024 + d] = f2bf(cacc[nt][r]);
        }
}

// ---------------- launcher ----------------
extern "C" void kernel_launch(void* const* d_in, const int* in_sizes, int n_in,
                              void* d_out, int out_size, void* d_ws, size_t ws_size,
                              hipStream_t stream)
{
    const float* v_in = (const float*)d_in[0];
    const float* k_in = (const float*)d_in[1];
    const float* q_in = (const float*)d_in[2];
    const float* mask = (const float*)d_in[3];
    const float* Wq = (const float*)d_in[4];
    const float* bq = (const float*)d_in[5];
    const float* Wk = (const float*)d_in[6];
    const float* bk = (const float*)d_in[7];
    const float* Wv = (const float*)d_in[8];
    const float* bv = (const float*)d_in[9];
    const float* Wo = (const float*)d_in[10];
    const float* bo = (const float*)d_in[11];

    float* out  = (float*)d_out;                    // [2,2048,1024]
    float* attn = out + (size_t)4194304;            // [2,16,2048,2048] = 512 MB

    unsigned char* ws = (unsigned char*)d_ws;       // 40 MB used
    unsigned short* wt     = (unsigned short*)(ws);                         // 8 MB (q,k,v,o)
    unsigned short* q_hi   = (unsigned short*)(ws + (size_t)(8)  * 1048576);
    unsigned short* k_hi   = (unsigned short*)(ws + (size_t)(16) * 1048576);
    unsigned short* v_hi   = (unsigned short*)(ws + (size_t)(24) * 1048576);
    unsigned short* ctx_hi = (unsigned short*)(ws + (size_t)(32) * 1048576);

    // dead scratch inside the attn output region (overwritten by attn_kernel later)
    unsigned short* a_hi   = (unsigned short*)(attn + (size_t)60 * 1048576);  // 24 MB

    prep_w_kernel<<<dim3(16, 16, 4), 256, 0, stream>>>(Wq, Wk, Wv, Wo, wt);
    prep_a_kernel<<<3072, 256, 0, stream>>>(q_in, k_in, v_in, a_hi);
    qkv_gemm_kernel<<<768, 256, 0, stream>>>(a_hi, wt, bq, bk, bv, q_hi, k_hi, v_hi);
    attn_kernel<<<1024, 256, 0, stream>>>(q_hi, k_hi, v_hi, mask, attn, ctx_hi);
    out_gemm_kernel<<<256, 256, 0, stream>>>(ctx_hi, wt + (size_t)3 * 1048576, bo, out);
}